// Round 7
// baseline (178.049 us; speedup 1.0000x reference)
//
#include <hip/hip_runtime.h>
#include <cstdint>

#define PERB 262144   // C*H*H = N*D elements per batch

typedef __attribute__((ext_vector_type(8))) short bf16x8;
typedef __attribute__((ext_vector_type(4))) float f32x4;
typedef unsigned short ushort_t;

__device__ __forceinline__ uint16_t f2bf(float f) {
    uint32_t u = __float_as_uint(f);
    u += 0x7fff + ((u >> 16) & 1);   // RNE
    return (uint16_t)(u >> 16);
}

// async global->LDS, 16B per lane. LDS dest is wave-uniform base (+lane*16 by HW);
// global src is per-lane.
__device__ __forceinline__ void glds16(const void* g, void* l) {
    __builtin_amdgcn_global_load_lds(
        (const __attribute__((address_space(1))) void*)g,
        (__attribute__((address_space(3))) void*)l, 16, 0, 0);
}

// ---------------------------------------------------------------------------
// Kernel 0: fused prep.
//   blocks [0,256)   : convert the 4 weight matrices (256x256 fp32) to bf16
//   blocks [256,768) : LayerNorm over channel axis -> bf16 X
// ---------------------------------------------------------------------------
__global__ __launch_bounds__(256) void prep_kernel(
    const float* __restrict__ x, const float* __restrict__ gam,
    const float* __restrict__ bet, ushort_t* __restrict__ X,
    const float* __restrict__ wq, const float* __restrict__ wk,
    const float* __restrict__ wv, const float* __restrict__ wo,
    ushort_t* __restrict__ oq, ushort_t* __restrict__ ok,
    ushort_t* __restrict__ ov, ushort_t* __restrict__ oo)
{
    const int blk = blockIdx.x;
    const int tid = threadIdx.x;
    if (blk < 256) {
        const int which = blk >> 6;
        const int idx = ((blk & 63) * 256 + tid) * 4;
        const float* src = which == 0 ? wq : which == 1 ? wk : which == 2 ? wv : wo;
        ushort_t* dst    = which == 0 ? oq : which == 1 ? ok : which == 2 ? ov : oo;
        const float4 v = *(const float4*)&src[idx];
        uint2 p;
        p.x = (uint32_t)f2bf(v.x) | ((uint32_t)f2bf(v.y) << 16);
        p.y = (uint32_t)f2bf(v.z) | ((uint32_t)f2bf(v.w) << 16);
        *(uint2*)&dst[idx] = p;
        return;
    }
    const int lb  = blk - 256;            // 512 blocks
    const int b   = lb >> 5;
    const int sp0 = (lb & 31) << 5;
    const int spl = tid & 31;
    const int cg  = tid >> 5;
    const int c0  = cg << 5;
    const int sp  = sp0 + spl;
    const float* xb = x + (size_t)b * PERB + sp;

    float vals[32];
    float s = 0.f, sq = 0.f;
#pragma unroll
    for (int i = 0; i < 32; ++i) {
        float v = xb[(size_t)(c0 + i) * 1024];
        vals[i] = v; s += v; sq += v * v;
    }
    __shared__ float rs[8][32];
    __shared__ float rq[8][32];
    rs[cg][spl] = s; rq[cg][spl] = sq;
    __syncthreads();
    float ts = 0.f, tq = 0.f;
#pragma unroll
    for (int g = 0; g < 8; ++g) { ts += rs[g][spl]; tq += rq[g][spl]; }
    const float mean = ts * (1.f / 256.f);
    const float var  = tq * (1.f / 256.f) - mean * mean;
    const float rstd = rsqrtf(var + 1e-5f);

    ushort_t* Xb = X + (size_t)b * PERB + sp;
#pragma unroll
    for (int i = 0; i < 32; ++i) {
        const int cc = c0 + i;
        Xb[(size_t)cc * 1024] = f2bf((vals[i] - mean) * rstd * gam[cc] + bet[cc]);
    }
}

// ---------------------------------------------------------------------------
// Kernel 2: MFMA fused Q/K/V projection — exact round-3 form (best measured).
// ---------------------------------------------------------------------------
__device__ __forceinline__ void qkv_stage(
    ushort_t* Sb, const ushort_t* __restrict__ X,
    const ushort_t* __restrict__ wq, const ushort_t* __restrict__ wk,
    const ushort_t* __restrict__ wv,
    int m0, int n0, int k0, int w, int lane)
{
    const int rsub = lane >> 3;          // 0..7  row-within-8-group
    const int u    = lane & 7;           // 16B unit within 128B row
    const int koct = u ^ rsub;           // pre-swizzled global k-octet
#pragma unroll
    for (int i = 0; i < 2; ++i) {
        const int rg  = w * 2 + i;       // 8-row group 0..7
        const int row = rg * 8 + rsub;   // row&7 == rsub
        const int go  = k0 + koct * 8;
        ushort_t* db = Sb + rg * 512;    // wave-uniform dest base (+lane*16B by HW)
        glds16(&X [(size_t)(m0 + row) * 256 + go], db);
        glds16(&wq[(size_t)(n0 + row) * 256 + go], db + 4096);
        glds16(&wk[(size_t)(n0 + row) * 256 + go], db + 8192);
        glds16(&wv[(size_t)(n0 + row) * 256 + go], db + 12288);
    }
}

__device__ __forceinline__ void qkv_compute(
    const ushort_t* Sb, int w, int c, int quad, f32x4 acc[3][4])
{
#pragma unroll
    for (int ks = 0; ks < 2; ++ks) {
        const int kq = ks * 4 + quad;
        const int uo = (kq ^ (c & 7)) * 8;
        bf16x8 af[4];
#pragma unroll
        for (int msub = 0; msub < 4; ++msub)
            af[msub] = *(const bf16x8*)&Sb[(msub * 16 + c) * 64 + uo];
        bf16x8 bw[3];
#pragma unroll
        for (int o3 = 0; o3 < 3; ++o3)
            bw[o3] = *(const bf16x8*)&Sb[(o3 + 1) * 4096 + (w * 16 + c) * 64 + uo];
#pragma unroll
        for (int o3 = 0; o3 < 3; ++o3)
#pragma unroll
            for (int msub = 0; msub < 4; ++msub)
                acc[o3][msub] = __builtin_amdgcn_mfma_f32_16x16x32_bf16(
                    bw[o3], af[msub], acc[o3][msub], 0, 0, 0);
    }
}

__global__ __launch_bounds__(256) void qkv_kernel(
    const ushort_t* __restrict__ X,
    const ushort_t* __restrict__ wq, const float* __restrict__ bq,
    const ushort_t* __restrict__ wk, const float* __restrict__ bk,
    const ushort_t* __restrict__ wv, const float* __restrict__ bv,
    ushort_t* __restrict__ Q, ushort_t* __restrict__ K, ushort_t* __restrict__ V)
{
    __shared__ __align__(16) ushort_t SB0[4][4096];
    __shared__ __align__(16) ushort_t SB1[4][4096];

    const int blk = blockIdx.x;
    const int m0  = (blk >> 2) << 6;
    const int n0  = (blk & 3) << 6;
    const int tid = threadIdx.x;
    const int w    = tid >> 6;
    const int lane = tid & 63;
    const int quad = lane >> 4;
    const int c    = lane & 15;

    f32x4 acc[3][4];
#pragma unroll
    for (int o3 = 0; o3 < 3; ++o3)
#pragma unroll
        for (int i = 0; i < 4; ++i) acc[o3][i] = (f32x4){0.f, 0.f, 0.f, 0.f};

    qkv_stage(&SB0[0][0], X, wq, wk, wv, m0, n0, 0, w, lane);
    __syncthreads();
#pragma unroll
    for (int kc = 0; kc < 4; ++kc) {
        if (kc < 3) {
            if ((kc & 1) == 0)
                qkv_stage(&SB1[0][0], X, wq, wk, wv, m0, n0, (kc + 1) << 6, w, lane);
            else
                qkv_stage(&SB0[0][0], X, wq, wk, wv, m0, n0, (kc + 1) << 6, w, lane);
        }
        if ((kc & 1) == 0) qkv_compute(&SB0[0][0], w, c, quad, acc);
        else               qkv_compute(&SB1[0][0], w, c, quad, acc);
        __syncthreads();
    }

    const int n = n0 + w * 16 + quad * 4;
    const float4 bq4 = *(const float4*)&bq[n];
    const float4 bk4 = *(const float4*)&bk[n];
    const float4 bv4 = *(const float4*)&bv[n];
    ushort_t* outs[3] = {Q, K, V};
    const float4 bias[3] = {bq4, bk4, bv4};
#pragma unroll
    for (int msub = 0; msub < 4; ++msub) {
        const size_t m = (size_t)(m0 + msub * 16 + c);
#pragma unroll
        for (int o3 = 0; o3 < 3; ++o3) {
            const f32x4 a = acc[o3][msub];
            uint2 p;
            p.x = (uint32_t)f2bf(a[0] + bias[o3].x) | ((uint32_t)f2bf(a[1] + bias[o3].y) << 16);
            p.y = (uint32_t)f2bf(a[2] + bias[o3].z) | ((uint32_t)f2bf(a[3] + bias[o3].w) << 16);
            *(uint2*)&outs[o3][m * 256 + n] = p;
        }
    }
}

// ---------------------------------------------------------------------------
// Kernel 3: MFMA flash attention — exact round-0 form (best measured 47.2us),
// launched as TWO half-grids (mt 0-3 and 4-7) via blk_off. Diagnostic round:
// each half ~24us, so qkv/oproj/prep outrank them in the top-5 duration table
// and surface with full counters for the first time.
// ---------------------------------------------------------------------------
#define C1F 0.09016844005556022f   // 0.0625 * log2(e)
#define LOG2EF 1.4426950408889634f

__global__ __launch_bounds__(256, 4) void attn_kernel(
    const ushort_t* __restrict__ Q, const ushort_t* __restrict__ K,
    const ushort_t* __restrict__ V, const float* __restrict__ relb,
    ushort_t* __restrict__ O, int blk_off)
{
    // LDS map (bytes):
    //   [0, 16384)       P: 128 rows x 128B, 16B-unit swizzle; Q staging at start
    //   [16384, 20480)   K: granule (q=s>>3)*1024 + nn*16
    //   [20480, 28672)   V dbuf: buf*4096 + s*128, 16B-unit swizzle ^(s&7)
    __shared__ __align__(16) unsigned char smem[28672];
    char* Pb = (char*)smem;
    char* Kl = (char*)(smem + 16384);
    char* Vl = (char*)(smem + 20480);

    const int blk = blockIdx.x + blk_off;
    const int bh  = blk & 127;
    const int mt  = blk >> 7;
    const int b   = bh >> 3;
    const int h   = bh & 7;
    const int m0  = mt << 7;
    const int tid = threadIdx.x;
    const int w    = tid >> 6;
    const int lane = tid & 63;
    const int quad = lane >> 4;
    const int c    = lane & 15;

    const size_t base = (size_t)b * PERB + (size_t)h * 32768;
    const ushort_t* Qg = Q + base;
    const ushort_t* Kg = K + base;
    const ushort_t* Vg = V + base;
    const float* rbh = relb + h * 3969;

    // ---- stage Q [32s x 128m] into Pb (granule layout), then read frags ----
    {
        const int mm = tid & 127;
        const int sg = tid >> 7;
        union { bf16x8 v; uint16_t u[8]; } g0, g1;
#pragma unroll
        for (int j = 0; j < 8; ++j)
            g0.u[j] = Qg[(size_t)(sg * 16 + j) * 1024 + m0 + mm];
#pragma unroll
        for (int j = 0; j < 8; ++j)
            g1.u[j] = Qg[(size_t)(sg * 16 + 8 + j) * 1024 + m0 + mm];
        *(bf16x8*)(Pb + (sg * 2 + 0) * 2048 + mm * 16) = g0.v;
        *(bf16x8*)(Pb + (sg * 2 + 1) * 2048 + mm * 16) = g1.v;
    }
    __syncthreads();
    bf16x8 qfrag[8];
#pragma unroll
    for (int msub = 0; msub < 8; ++msub)
        qfrag[msub] = *(const bf16x8*)(Pb + quad * 2048 + (msub * 16 + c) * 16);

    // per-msub bias m-offset: idx = noff(n) + moff(m)
    int moff[8];
#pragma unroll
    for (int msub = 0; msub < 8; ++msub) {
        const int m = m0 + msub * 16 + c;
        moff[msub] = 1984 - (m >> 5) * 63 - (m & 31);
    }

    // accumulators
    f32x4 oacc[2][2], dacc[2];
#pragma unroll
    for (int i = 0; i < 2; ++i) {
        dacc[i] = (f32x4){0.f, 0.f, 0.f, 0.f};
#pragma unroll
        for (int j = 0; j < 2; ++j) oacc[i][j] = (f32x4){0.f, 0.f, 0.f, 0.f};
    }
    bf16x8 onesf;
#pragma unroll
    for (int j = 0; j < 8; ++j) onesf[j] = (short)0x3F80;

    // staging thread coords + hoisted LDS addresses
    const int knn = tid & 63, ksg = tid >> 6;   // K: 8 s-values for column knn
    const int vs  = tid >> 3, vng = tid & 7;    // V: unit16 vng of row vs
    const int kWr = ksg * 1024 + knn * 16;
    const int vWr = vs * 128 + ((vng ^ (vs & 7)) << 4);
    const int kRd = quad * 1024 + (w * 16 + c) * 16;
    const int pWr = c * 128 + (((2 * w + (quad >> 1)) ^ (c & 7)) << 4) + ((quad & 1) << 3);
    const int c7  = c & 7;

    // prologue: prefetch chunk 0
    uint32_t kpre[8]; bf16x8 vpre;
#pragma unroll
    for (int j = 0; j < 8; ++j) kpre[j] = Kg[(size_t)(ksg * 8 + j) * 1024 + knn];
    vpre = *(const bf16x8*)&Vg[(size_t)vs * 1024 + vng * 8];

    for (int ch = 0; ch < 16; ++ch) {
        const int n0c = ch << 6;
        const int cb  = ch & 1;

        // ---- write prefetched K/V to LDS ----
        {
            uint4 kp;
            kp.x = kpre[0] | (kpre[1] << 16);
            kp.y = kpre[2] | (kpre[3] << 16);
            kp.z = kpre[4] | (kpre[5] << 16);
            kp.w = kpre[6] | (kpre[7] << 16);
            *(uint4*)(Kl + kWr) = kp;
            *(bf16x8*)(Vl + cb * 4096 + vWr) = vpre;
        }
        __syncthreads();   // staging visible; prev PV done for all waves

        // ---- prefetch next chunk into regs (overlaps S phase) ----
        {
            const int n0n = ((ch + 1) & 15) << 6;
#pragma unroll
            for (int j = 0; j < 8; ++j)
                kpre[j] = Kg[(size_t)(ksg * 8 + j) * 1024 + n0n + knn];
            vpre = *(const bf16x8*)&Vg[(size_t)vs * 1024 + n0n + vng * 8];
        }

        // ---- S phase ----
        const bf16x8 kf = *(const bf16x8*)(Kl + kRd);
        f32x4 sacc[8];
#pragma unroll
        for (int msub = 0; msub < 8; ++msub) {
            const f32x4 z = {0.f, 0.f, 0.f, 0.f};
            sacc[msub] = __builtin_amdgcn_mfma_f32_16x16x32_bf16(kf, qfrag[msub], z, 0, 0, 0);
        }

        // ---- bias (global, L1/L2-hit) + exp2 + trunc-pack + P write ----
        const int nbase = n0c + w * 16 + quad * 4;
        const int nidx0 = (nbase >> 5) * 63 + (nbase & 31);  // 4 consecutive ints follow
#pragma unroll
        for (int msub = 0; msub < 8; ++msub) {
            const float* bp = rbh + nidx0 + moff[msub];
            float p[4];
#pragma unroll
            for (int r = 0; r < 4; ++r)
                p[r] = __builtin_amdgcn_exp2f(fmaf(bp[r], LOG2EF, sacc[msub][r] * C1F));
            uint2 pk;
            pk.x = __builtin_amdgcn_perm(__float_as_uint(p[1]), __float_as_uint(p[0]), 0x07060302u);
            pk.y = __builtin_amdgcn_perm(__float_as_uint(p[3]), __float_as_uint(p[2]), 0x07060302u);
            *(uint2*)(Pb + msub * 2048 + pWr) = pk;
        }
        __syncthreads();   // P (and V) ready for PV

        // ---- PV phase: wave w owns msub {2w, 2w+1} ----
#pragma unroll
        for (int kstep = 0; kstep < 2; ++kstep) {
            const int u = ((kstep * 4 + quad) ^ c7) << 4;
            const bf16x8 vf0 = *(const bf16x8*)(Vl + cb * 4096 + c * 128 + u);
            const bf16x8 vf1 = *(const bf16x8*)(Vl + cb * 4096 + (16 + c) * 128 + u);
#pragma unroll
            for (int mi = 0; mi < 2; ++mi) {
                const bf16x8 pf = *(const bf16x8*)(Pb + ((w * 2 + mi) * 16 + c) * 128 + u);
                oacc[0][mi] = __builtin_amdgcn_mfma_f32_16x16x32_bf16(vf0, pf, oacc[0][mi], 0, 0, 0);
                oacc[1][mi] = __builtin_amdgcn_mfma_f32_16x16x32_bf16(vf1, pf, oacc[1][mi], 0, 0, 0);
                dacc[mi]    = __builtin_amdgcn_mfma_f32_16x16x32_bf16(onesf, pf, dacc[mi], 0, 0, 0);
            }
        }
    }

    // ---- epilogue: scale by 1/denominator, write O ----
    ushort_t* Ob = O + base;
#pragma unroll
    for (int mi = 0; mi < 2; ++mi) {
        const float inv = 1.0f / dacc[mi][0];
        const int m = m0 + (w * 2 + mi) * 16 + c;
#pragma unroll
        for (int ssub = 0; ssub < 2; ++ssub)
#pragma unroll
            for (int r = 0; r < 4; ++r)
                Ob[(size_t)(ssub * 16 + quad * 4 + r) * 1024 + m] = f2bf(oacc[ssub][mi][r] * inv);
    }
}

// ---------------------------------------------------------------------------
// Kernel 4: MFMA output projection + bias + residual — exact round-3 form.
// ---------------------------------------------------------------------------
__device__ __forceinline__ void oproj_stage(
    ushort_t* Sb, const ushort_t* __restrict__ A, const ushort_t* __restrict__ wo,
    int m0, int n0, int k0, int w, int lane)
{
    const int rsub = lane >> 3;
    const int u    = lane & 7;
    const int koct = u ^ rsub;
#pragma unroll
    for (int i = 0; i < 2; ++i) {
        const int rg  = w * 2 + i;
        const int row = rg * 8 + rsub;
        const int go  = k0 + koct * 8;
        ushort_t* db = Sb + rg * 512;
        glds16(&A [(size_t)(m0 + row) * 256 + go], db);
        glds16(&wo[(size_t)(n0 + row) * 256 + go], db + 4096);
    }
}

__device__ __forceinline__ void oproj_compute(
    const ushort_t* Sb, int w, int c, int quad, f32x4 acc[4])
{
#pragma unroll
    for (int ks = 0; ks < 2; ++ks) {
        const int kq = ks * 4 + quad;
        const int uo = (kq ^ (c & 7)) * 8;
        const bf16x8 bw = *(const bf16x8*)&Sb[4096 + (w * 16 + c) * 64 + uo];
#pragma unroll
        for (int msub = 0; msub < 4; ++msub) {
            const bf16x8 af = *(const bf16x8*)&Sb[(msub * 16 + c) * 64 + uo];
            acc[msub] = __builtin_amdgcn_mfma_f32_16x16x32_bf16(bw, af, acc[msub], 0, 0, 0);
        }
    }
}

__global__ __launch_bounds__(256, 4) void oproj_kernel(
    const ushort_t* __restrict__ A, const ushort_t* __restrict__ wo,
    const float* __restrict__ bo, const float* __restrict__ x,
    float* __restrict__ out)
{
    __shared__ __align__(16) ushort_t SA0[2][4096];
    __shared__ __align__(16) ushort_t SA1[2][4096];

    const int blk = blockIdx.x;
    const int m0  = (blk >> 2) << 6;
    const int n0  = (blk & 3) << 6;
    const int tid = threadIdx.x;
    const int w    = tid >> 6;
    const int lane = tid & 63;
    const int quad = lane >> 4;
    const int c    = lane & 15;

    f32x4 acc[4];
#pragma unroll
    for (int i = 0; i < 4; ++i) acc[i] = (f32x4){0.f, 0.f, 0.f, 0.f};

    oproj_stage(&SA0[0][0], A, wo, m0, n0, 0, w, lane);
    __syncthreads();
#pragma unroll
    for (int kc = 0; kc < 4; ++kc) {
        if (kc < 3) {
            if ((kc & 1) == 0)
                oproj_stage(&SA1[0][0], A, wo, m0, n0, (kc + 1) << 6, w, lane);
            else
                oproj_stage(&SA0[0][0], A, wo, m0, n0, (kc + 1) << 6, w, lane);
        }
        if ((kc & 1) == 0) oproj_compute(&SA0[0][0], w, c, quad, acc);
        else               oproj_compute(&SA1[0][0], w, c, quad, acc);
        __syncthreads();
    }

    const int n = n0 + w * 16 + quad * 4;
    const float4 bo4 = *(const float4*)&bo[n];
#pragma unroll
    for (int msub = 0; msub < 4; ++msub) {
        const size_t g = (size_t)(m0 + msub * 16 + c) * 256 + n;
        const float4 r = *(const float4*)&x[g];
        float4 t;
        t.x = acc[msub][0] + bo4.x + r.x;
        t.y = acc[msub][1] + bo4.y + r.y;
        t.z = acc[msub][2] + bo4.z + r.z;
        t.w = acc[msub][3] + bo4.w + r.w;
        *(float4*)&out[g] = t;
    }
}

// ---------------------------------------------------------------------------
extern "C" void kernel_launch(void* const* d_in, const int* in_sizes, int n_in,
                              void* d_out, int out_size, void* d_ws, size_t ws_size,
                              hipStream_t stream)
{
    (void)in_sizes; (void)n_in; (void)out_size; (void)ws_size;
    const float* x   = (const float*)d_in[0];
    const float* lng = (const float*)d_in[1];
    const float* lnb = (const float*)d_in[2];
    const float* wq  = (const float*)d_in[3];
    const float* bq  = (const float*)d_in[4];
    const float* wk  = (const float*)d_in[5];
    const float* bk  = (const float*)d_in[6];
    const float* wv  = (const float*)d_in[7];
    const float* bv  = (const float*)d_in[8];
    const float* wo  = (const float*)d_in[9];
    const float* bo  = (const float*)d_in[10];
    const float* rb  = (const float*)d_in[11];
    // d_in[12] (rel_idx) unused: index recomputed analytically in-kernel.

    ushort_t* ws = (ushort_t*)d_ws;
    ushort_t* Xbf = ws;                       // 4194304 elems each
    ushort_t* Qbf = ws + 1 * 4194304;
    ushort_t* Kbf = ws + 2 * 4194304;
    ushort_t* Vbf = ws + 3 * 4194304;
    ushort_t* Obf = ws + 4 * 4194304;
    ushort_t* Wqb = ws + 5 * 4194304;
    ushort_t* Wkb = Wqb + 65536;
    ushort_t* Wvb = Wkb + 65536;
    ushort_t* Wob = Wvb + 65536;
    float* out = (float*)d_out;

    hipLaunchKernelGGL(prep_kernel,  dim3(768),  dim3(256), 0, stream,
                       x, lng, lnb, Xbf, wq, wk, wv, wo, Wqb, Wkb, Wvb, Wob);
    hipLaunchKernelGGL(qkv_kernel,   dim3(1024), dim3(256), 0, stream,
                       Xbf, Wqb, bq, Wkb, bk, Wvb, bv, Qbf, Kbf, Vbf);
    hipLaunchKernelGGL(attn_kernel,  dim3(512),  dim3(256), 0, stream,
                       Qbf, Kbf, Vbf, rb, Obf, 0);
    hipLaunchKernelGGL(attn_kernel,  dim3(512),  dim3(256), 0, stream,
                       Qbf, Kbf, Vbf, rb, Obf, 512);
    hipLaunchKernelGGL(oproj_kernel, dim3(1024), dim3(256), 0, stream, Obf, Wob, bo, x, out);
}

// Round 8
// 165.696 us; speedup vs baseline: 1.0746x; 1.0746x over previous
//
#include <hip/hip_runtime.h>
#include <cstdint>

#define PERB 262144   // C*H*H = N*D elements per batch

typedef __attribute__((ext_vector_type(8))) short bf16x8;
typedef __attribute__((ext_vector_type(4))) float f32x4;
typedef unsigned short ushort_t;

__device__ __forceinline__ uint16_t f2bf(float f) {
    uint32_t u = __float_as_uint(f);
    u += 0x7fff + ((u >> 16) & 1);   // RNE
    return (uint16_t)(u >> 16);
}

// async global->LDS, 16B per lane. LDS dest is wave-uniform base (+lane*16 by HW);
// global src is per-lane.
__device__ __forceinline__ void glds16(const void* g, void* l) {
    __builtin_amdgcn_global_load_lds(
        (const __attribute__((address_space(1))) void*)g,
        (__attribute__((address_space(3))) void*)l, 16, 0, 0);
}

// counted vmcnt wait: waits until at most N vector-memory ops are outstanding.
#define WAITVMCNT(N) asm volatile("s_waitcnt vmcnt(" #N ")" ::: "memory")

// ---------------------------------------------------------------------------
// Kernel 0: fused prep.
//   blocks [0,256)   : convert the 4 weight matrices (256x256 fp32) to bf16
//   blocks [256,768) : LayerNorm over channel axis -> bf16 X
// ---------------------------------------------------------------------------
__global__ __launch_bounds__(256) void prep_kernel(
    const float* __restrict__ x, const float* __restrict__ gam,
    const float* __restrict__ bet, ushort_t* __restrict__ X,
    const float* __restrict__ wq, const float* __restrict__ wk,
    const float* __restrict__ wv, const float* __restrict__ wo,
    ushort_t* __restrict__ oq, ushort_t* __restrict__ ok,
    ushort_t* __restrict__ ov, ushort_t* __restrict__ oo)
{
    const int blk = blockIdx.x;
    const int tid = threadIdx.x;
    if (blk < 256) {
        const int which = blk >> 6;
        const int idx = ((blk & 63) * 256 + tid) * 4;
        const float* src = which == 0 ? wq : which == 1 ? wk : which == 2 ? wv : wo;
        ushort_t* dst    = which == 0 ? oq : which == 1 ? ok : which == 2 ? ov : oo;
        const float4 v = *(const float4*)&src[idx];
        uint2 p;
        p.x = (uint32_t)f2bf(v.x) | ((uint32_t)f2bf(v.y) << 16);
        p.y = (uint32_t)f2bf(v.z) | ((uint32_t)f2bf(v.w) << 16);
        *(uint2*)&dst[idx] = p;
        return;
    }
    const int lb  = blk - 256;            // 512 blocks
    const int b   = lb >> 5;
    const int sp0 = (lb & 31) << 5;
    const int spl = tid & 31;
    const int cg  = tid >> 5;
    const int c0  = cg << 5;
    const int sp  = sp0 + spl;
    const float* xb = x + (size_t)b * PERB + sp;

    float vals[32];
    float s = 0.f, sq = 0.f;
#pragma unroll
    for (int i = 0; i < 32; ++i) {
        float v = xb[(size_t)(c0 + i) * 1024];
        vals[i] = v; s += v; sq += v * v;
    }
    __shared__ float rs[8][32];
    __shared__ float rq[8][32];
    rs[cg][spl] = s; rq[cg][spl] = sq;
    __syncthreads();
    float ts = 0.f, tq = 0.f;
#pragma unroll
    for (int g = 0; g < 8; ++g) { ts += rs[g][spl]; tq += rq[g][spl]; }
    const float mean = ts * (1.f / 256.f);
    const float var  = tq * (1.f / 256.f) - mean * mean;
    const float rstd = rsqrtf(var + 1e-5f);

    ushort_t* Xb = X + (size_t)b * PERB + sp;
#pragma unroll
    for (int i = 0; i < 32; ++i) {
        const int cc = c0 + i;
        Xb[(size_t)cc * 1024] = f2bf((vals[i] - mean) * rstd * gam[cc] + bet[cc]);
    }
}

// ---------------------------------------------------------------------------
// Kernel 2: MFMA fused Q/K/V projection, round-15.
//  Same r3 tiles/staging, but the K-loop barrier no longer drains the
//  just-issued prefetch: counted `s_waitcnt vmcnt(8)` + raw s_barrier
//  (T4 pattern). Previously __syncthreads emitted vmcnt(0) and serialized
//  every kc on the full L2 round-trip — the double-buffer overlapped nothing.
//  Ledger: per-iter loads (8/thread) target the buffer nobody reads this
//  phase; vmcnt(8) retires the PREVIOUS iter's loads before barrier-1;
//  barrier-2 separates compute-reads from next iter's stage-writes.
// ---------------------------------------------------------------------------
__device__ __forceinline__ void qkv_stage(
    ushort_t* Sb, const ushort_t* __restrict__ X,
    const ushort_t* __restrict__ wq, const ushort_t* __restrict__ wk,
    const ushort_t* __restrict__ wv,
    int m0, int n0, int k0, int w, int lane)
{
    const int rsub = lane >> 3;          // 0..7  row-within-8-group
    const int u    = lane & 7;           // 16B unit within 128B row
    const int koct = u ^ rsub;           // pre-swizzled global k-octet
#pragma unroll
    for (int i = 0; i < 2; ++i) {
        const int rg  = w * 2 + i;       // 8-row group 0..7
        const int row = rg * 8 + rsub;   // row&7 == rsub
        const int go  = k0 + koct * 8;
        ushort_t* db = Sb + rg * 512;    // wave-uniform dest base (+lane*16B by HW)
        glds16(&X [(size_t)(m0 + row) * 256 + go], db);
        glds16(&wq[(size_t)(n0 + row) * 256 + go], db + 4096);
        glds16(&wk[(size_t)(n0 + row) * 256 + go], db + 8192);
        glds16(&wv[(size_t)(n0 + row) * 256 + go], db + 12288);
    }
}

__device__ __forceinline__ void qkv_compute(
    const ushort_t* Sb, int w, int c, int quad, f32x4 acc[3][4])
{
#pragma unroll
    for (int ks = 0; ks < 2; ++ks) {
        const int kq = ks * 4 + quad;
        const int uo = (kq ^ (c & 7)) * 8;
        bf16x8 af[4];
#pragma unroll
        for (int msub = 0; msub < 4; ++msub)
            af[msub] = *(const bf16x8*)&Sb[(msub * 16 + c) * 64 + uo];
        bf16x8 bw[3];
#pragma unroll
        for (int o3 = 0; o3 < 3; ++o3)
            bw[o3] = *(const bf16x8*)&Sb[(o3 + 1) * 4096 + (w * 16 + c) * 64 + uo];
#pragma unroll
        for (int o3 = 0; o3 < 3; ++o3)
#pragma unroll
            for (int msub = 0; msub < 4; ++msub)
                acc[o3][msub] = __builtin_amdgcn_mfma_f32_16x16x32_bf16(
                    bw[o3], af[msub], acc[o3][msub], 0, 0, 0);
    }
}

__global__ __launch_bounds__(256) void qkv_kernel(
    const ushort_t* __restrict__ X,
    const ushort_t* __restrict__ wq, const float* __restrict__ bq,
    const ushort_t* __restrict__ wk, const float* __restrict__ bk,
    const ushort_t* __restrict__ wv, const float* __restrict__ bv,
    ushort_t* __restrict__ Q, ushort_t* __restrict__ K, ushort_t* __restrict__ V)
{
    __shared__ __align__(16) ushort_t SB0[4][4096];
    __shared__ __align__(16) ushort_t SB1[4][4096];

    const int blk = blockIdx.x;
    const int m0  = (blk >> 2) << 6;
    const int n0  = (blk & 3) << 6;
    const int tid = threadIdx.x;
    const int w    = tid >> 6;
    const int lane = tid & 63;
    const int quad = lane >> 4;
    const int c    = lane & 15;

    f32x4 acc[3][4];
#pragma unroll
    for (int o3 = 0; o3 < 3; ++o3)
#pragma unroll
        for (int i = 0; i < 4; ++i) acc[o3][i] = (f32x4){0.f, 0.f, 0.f, 0.f};

    // prologue: stage kc=0 into SB0
    qkv_stage(&SB0[0][0], X, wq, wk, wv, m0, n0, 0, w, lane);

    // kc = 0: prefetch kc=1 -> SB1, compute SB0
    qkv_stage(&SB1[0][0], X, wq, wk, wv, m0, n0, 64, w, lane);
    WAITVMCNT(8);
    __builtin_amdgcn_s_barrier();
    __builtin_amdgcn_sched_barrier(0);
    qkv_compute(&SB0[0][0], w, c, quad, acc);
    __builtin_amdgcn_s_barrier();

    // kc = 1: prefetch kc=2 -> SB0, compute SB1
    qkv_stage(&SB0[0][0], X, wq, wk, wv, m0, n0, 128, w, lane);
    WAITVMCNT(8);
    __builtin_amdgcn_s_barrier();
    __builtin_amdgcn_sched_barrier(0);
    qkv_compute(&SB1[0][0], w, c, quad, acc);
    __builtin_amdgcn_s_barrier();

    // kc = 2: prefetch kc=3 -> SB1, compute SB0
    qkv_stage(&SB1[0][0], X, wq, wk, wv, m0, n0, 192, w, lane);
    WAITVMCNT(8);
    __builtin_amdgcn_s_barrier();
    __builtin_amdgcn_sched_barrier(0);
    qkv_compute(&SB0[0][0], w, c, quad, acc);
    __builtin_amdgcn_s_barrier();

    // kc = 3: compute SB1 (drain remaining loads)
    WAITVMCNT(0);
    __builtin_amdgcn_s_barrier();
    __builtin_amdgcn_sched_barrier(0);
    qkv_compute(&SB1[0][0], w, c, quad, acc);

    const int n = n0 + w * 16 + quad * 4;
    const float4 bq4 = *(const float4*)&bq[n];
    const float4 bk4 = *(const float4*)&bk[n];
    const float4 bv4 = *(const float4*)&bv[n];
    ushort_t* outs[3] = {Q, K, V};
    const float4 bias[3] = {bq4, bk4, bv4};
#pragma unroll
    for (int msub = 0; msub < 4; ++msub) {
        const size_t m = (size_t)(m0 + msub * 16 + c);
#pragma unroll
        for (int o3 = 0; o3 < 3; ++o3) {
            const f32x4 a = acc[o3][msub];
            uint2 p;
            p.x = (uint32_t)f2bf(a[0] + bias[o3].x) | ((uint32_t)f2bf(a[1] + bias[o3].y) << 16);
            p.y = (uint32_t)f2bf(a[2] + bias[o3].z) | ((uint32_t)f2bf(a[3] + bias[o3].w) << 16);
            *(uint2*)&outs[o3][m * 256 + n] = p;
        }
    }
}

// ---------------------------------------------------------------------------
// Kernel 3: MFMA flash attention — exact round-0 form (best measured 47.2us),
// single 1024-block launch (r7 split to 512-block halves cost ~17us: 2 blk/CU).
// ---------------------------------------------------------------------------
#define C1F 0.09016844005556022f   // 0.0625 * log2(e)
#define LOG2EF 1.4426950408889634f

__global__ __launch_bounds__(256, 4) void attn_kernel(
    const ushort_t* __restrict__ Q, const ushort_t* __restrict__ K,
    const ushort_t* __restrict__ V, const float* __restrict__ relb,
    ushort_t* __restrict__ O)
{
    // LDS map (bytes):
    //   [0, 16384)       P: 128 rows x 128B, 16B-unit swizzle; Q staging at start
    //   [16384, 20480)   K: granule (q=s>>3)*1024 + nn*16
    //   [20480, 28672)   V dbuf: buf*4096 + s*128, 16B-unit swizzle ^(s&7)
    __shared__ __align__(16) unsigned char smem[28672];
    char* Pb = (char*)smem;
    char* Kl = (char*)(smem + 16384);
    char* Vl = (char*)(smem + 20480);

    const int blk = blockIdx.x;
    const int bh  = blk & 127;
    const int mt  = blk >> 7;
    const int b   = bh >> 3;
    const int h   = bh & 7;
    const int m0  = mt << 7;
    const int tid = threadIdx.x;
    const int w    = tid >> 6;
    const int lane = tid & 63;
    const int quad = lane >> 4;
    const int c    = lane & 15;

    const size_t base = (size_t)b * PERB + (size_t)h * 32768;
    const ushort_t* Qg = Q + base;
    const ushort_t* Kg = K + base;
    const ushort_t* Vg = V + base;
    const float* rbh = relb + h * 3969;

    // ---- stage Q [32s x 128m] into Pb (granule layout), then read frags ----
    {
        const int mm = tid & 127;
        const int sg = tid >> 7;
        union { bf16x8 v; uint16_t u[8]; } g0, g1;
#pragma unroll
        for (int j = 0; j < 8; ++j)
            g0.u[j] = Qg[(size_t)(sg * 16 + j) * 1024 + m0 + mm];
#pragma unroll
        for (int j = 0; j < 8; ++j)
            g1.u[j] = Qg[(size_t)(sg * 16 + 8 + j) * 1024 + m0 + mm];
        *(bf16x8*)(Pb + (sg * 2 + 0) * 2048 + mm * 16) = g0.v;
        *(bf16x8*)(Pb + (sg * 2 + 1) * 2048 + mm * 16) = g1.v;
    }
    __syncthreads();
    bf16x8 qfrag[8];
#pragma unroll
    for (int msub = 0; msub < 8; ++msub)
        qfrag[msub] = *(const bf16x8*)(Pb + quad * 2048 + (msub * 16 + c) * 16);

    // per-msub bias m-offset: idx = noff(n) + moff(m)
    int moff[8];
#pragma unroll
    for (int msub = 0; msub < 8; ++msub) {
        const int m = m0 + msub * 16 + c;
        moff[msub] = 1984 - (m >> 5) * 63 - (m & 31);
    }

    // accumulators
    f32x4 oacc[2][2], dacc[2];
#pragma unroll
    for (int i = 0; i < 2; ++i) {
        dacc[i] = (f32x4){0.f, 0.f, 0.f, 0.f};
#pragma unroll
        for (int j = 0; j < 2; ++j) oacc[i][j] = (f32x4){0.f, 0.f, 0.f, 0.f};
    }
    bf16x8 onesf;
#pragma unroll
    for (int j = 0; j < 8; ++j) onesf[j] = (short)0x3F80;

    // staging thread coords + hoisted LDS addresses
    const int knn = tid & 63, ksg = tid >> 6;   // K: 8 s-values for column knn
    const int vs  = tid >> 3, vng = tid & 7;    // V: unit16 vng of row vs
    const int kWr = ksg * 1024 + knn * 16;
    const int vWr = vs * 128 + ((vng ^ (vs & 7)) << 4);
    const int kRd = quad * 1024 + (w * 16 + c) * 16;
    const int pWr = c * 128 + (((2 * w + (quad >> 1)) ^ (c & 7)) << 4) + ((quad & 1) << 3);
    const int c7  = c & 7;

    // prologue: prefetch chunk 0
    uint32_t kpre[8]; bf16x8 vpre;
#pragma unroll
    for (int j = 0; j < 8; ++j) kpre[j] = Kg[(size_t)(ksg * 8 + j) * 1024 + knn];
    vpre = *(const bf16x8*)&Vg[(size_t)vs * 1024 + vng * 8];

    for (int ch = 0; ch < 16; ++ch) {
        const int n0c = ch << 6;
        const int cb  = ch & 1;

        // ---- write prefetched K/V to LDS ----
        {
            uint4 kp;
            kp.x = kpre[0] | (kpre[1] << 16);
            kp.y = kpre[2] | (kpre[3] << 16);
            kp.z = kpre[4] | (kpre[5] << 16);
            kp.w = kpre[6] | (kpre[7] << 16);
            *(uint4*)(Kl + kWr) = kp;
            *(bf16x8*)(Vl + cb * 4096 + vWr) = vpre;
        }
        __syncthreads();   // staging visible; prev PV done for all waves

        // ---- prefetch next chunk into regs (overlaps S phase) ----
        {
            const int n0n = ((ch + 1) & 15) << 6;
#pragma unroll
            for (int j = 0; j < 8; ++j)
                kpre[j] = Kg[(size_t)(ksg * 8 + j) * 1024 + n0n + knn];
            vpre = *(const bf16x8*)&Vg[(size_t)vs * 1024 + n0n + vng * 8];
        }

        // ---- S phase ----
        const bf16x8 kf = *(const bf16x8*)(Kl + kRd);
        f32x4 sacc[8];
#pragma unroll
        for (int msub = 0; msub < 8; ++msub) {
            const f32x4 z = {0.f, 0.f, 0.f, 0.f};
            sacc[msub] = __builtin_amdgcn_mfma_f32_16x16x32_bf16(kf, qfrag[msub], z, 0, 0, 0);
        }

        // ---- bias (global, L1/L2-hit) + exp2 + trunc-pack + P write ----
        const int nbase = n0c + w * 16 + quad * 4;
        const int nidx0 = (nbase >> 5) * 63 + (nbase & 31);  // 4 consecutive ints follow
#pragma unroll
        for (int msub = 0; msub < 8; ++msub) {
            const float* bp = rbh + nidx0 + moff[msub];
            float p[4];
#pragma unroll
            for (int r = 0; r < 4; ++r)
                p[r] = __builtin_amdgcn_exp2f(fmaf(bp[r], LOG2EF, sacc[msub][r] * C1F));
            uint2 pk;
            pk.x = __builtin_amdgcn_perm(__float_as_uint(p[1]), __float_as_uint(p[0]), 0x07060302u);
            pk.y = __builtin_amdgcn_perm(__float_as_uint(p[3]), __float_as_uint(p[2]), 0x07060302u);
            *(uint2*)(Pb + msub * 2048 + pWr) = pk;
        }
        __syncthreads();   // P (and V) ready for PV

        // ---- PV phase: wave w owns msub {2w, 2w+1} ----
#pragma unroll
        for (int kstep = 0; kstep < 2; ++kstep) {
            const int u = ((kstep * 4 + quad) ^ c7) << 4;
            const bf16x8 vf0 = *(const bf16x8*)(Vl + cb * 4096 + c * 128 + u);
            const bf16x8 vf1 = *(const bf16x8*)(Vl + cb * 4096 + (16 + c) * 128 + u);
#pragma unroll
            for (int mi = 0; mi < 2; ++mi) {
                const bf16x8 pf = *(const bf16x8*)(Pb + ((w * 2 + mi) * 16 + c) * 128 + u);
                oacc[0][mi] = __builtin_amdgcn_mfma_f32_16x16x32_bf16(vf0, pf, oacc[0][mi], 0, 0, 0);
                oacc[1][mi] = __builtin_amdgcn_mfma_f32_16x16x32_bf16(vf1, pf, oacc[1][mi], 0, 0, 0);
                dacc[mi]    = __builtin_amdgcn_mfma_f32_16x16x32_bf16(onesf, pf, dacc[mi], 0, 0, 0);
            }
        }
    }

    // ---- epilogue: scale by 1/denominator, write O ----
    ushort_t* Ob = O + base;
#pragma unroll
    for (int mi = 0; mi < 2; ++mi) {
        const float inv = 1.0f / dacc[mi][0];
        const int m = m0 + (w * 2 + mi) * 16 + c;
#pragma unroll
        for (int ssub = 0; ssub < 2; ++ssub)
#pragma unroll
            for (int r = 0; r < 4; ++r)
                Ob[(size_t)(ssub * 16 + quad * 4 + r) * 1024 + m] = f2bf(oacc[ssub][mi][r] * inv);
    }
}

// ---------------------------------------------------------------------------
// Kernel 4: MFMA output projection + bias + residual — counted-vmcnt K-loop
// (same T4 rewrite as qkv; 4 glds/thread per stage).
// ---------------------------------------------------------------------------
__device__ __forceinline__ void oproj_stage(
    ushort_t* Sb, const ushort_t* __restrict__ A, const ushort_t* __restrict__ wo,
    int m0, int n0, int k0, int w, int lane)
{
    const int rsub = lane >> 3;
    const int u    = lane & 7;
    const int koct = u ^ rsub;
#pragma unroll
    for (int i = 0; i < 2; ++i) {
        const int rg  = w * 2 + i;
        const int row = rg * 8 + rsub;
        const int go  = k0 + koct * 8;
        ushort_t* db = Sb + rg * 512;
        glds16(&A [(size_t)(m0 + row) * 256 + go], db);
        glds16(&wo[(size_t)(n0 + row) * 256 + go], db + 4096);
    }
}

__device__ __forceinline__ void oproj_compute(
    const ushort_t* Sb, int w, int c, int quad, f32x4 acc[4])
{
#pragma unroll
    for (int ks = 0; ks < 2; ++ks) {
        const int kq = ks * 4 + quad;
        const int uo = (kq ^ (c & 7)) * 8;
        const bf16x8 bw = *(const bf16x8*)&Sb[4096 + (w * 16 + c) * 64 + uo];
#pragma unroll
        for (int msub = 0; msub < 4; ++msub) {
            const bf16x8 af = *(const bf16x8*)&Sb[(msub * 16 + c) * 64 + uo];
            acc[msub] = __builtin_amdgcn_mfma_f32_16x16x32_bf16(bw, af, acc[msub], 0, 0, 0);
        }
    }
}

__global__ __launch_bounds__(256, 4) void oproj_kernel(
    const ushort_t* __restrict__ A, const ushort_t* __restrict__ wo,
    const float* __restrict__ bo, const float* __restrict__ x,
    float* __restrict__ out)
{
    __shared__ __align__(16) ushort_t SA0[2][4096];
    __shared__ __align__(16) ushort_t SA1[2][4096];

    const int blk = blockIdx.x;
    const int m0  = (blk >> 2) << 6;
    const int n0  = (blk & 3) << 6;
    const int tid = threadIdx.x;
    const int w    = tid >> 6;
    const int lane = tid & 63;
    const int quad = lane >> 4;
    const int c    = lane & 15;

    f32x4 acc[4];
#pragma unroll
    for (int i = 0; i < 4; ++i) acc[i] = (f32x4){0.f, 0.f, 0.f, 0.f};

    // prologue: stage kc=0 into SA0
    oproj_stage(&SA0[0][0], A, wo, m0, n0, 0, w, lane);

    // kc = 0
    oproj_stage(&SA1[0][0], A, wo, m0, n0, 64, w, lane);
    WAITVMCNT(4);
    __builtin_amdgcn_s_barrier();
    __builtin_amdgcn_sched_barrier(0);
    oproj_compute(&SA0[0][0], w, c, quad, acc);
    __builtin_amdgcn_s_barrier();

    // kc = 1
    oproj_stage(&SA0[0][0], A, wo, m0, n0, 128, w, lane);
    WAITVMCNT(4);
    __builtin_amdgcn_s_barrier();
    __builtin_amdgcn_sched_barrier(0);
    oproj_compute(&SA1[0][0], w, c, quad, acc);
    __builtin_amdgcn_s_barrier();

    // kc = 2
    oproj_stage(&SA1[0][0], A, wo, m0, n0, 192, w, lane);
    WAITVMCNT(4);
    __builtin_amdgcn_s_barrier();
    __builtin_amdgcn_sched_barrier(0);
    oproj_compute(&SA0[0][0], w, c, quad, acc);
    __builtin_amdgcn_s_barrier();

    // kc = 3
    WAITVMCNT(0);
    __builtin_amdgcn_s_barrier();
    __builtin_amdgcn_sched_barrier(0);
    oproj_compute(&SA1[0][0], w, c, quad, acc);

    const int n = n0 + w * 16 + quad * 4;
    const float4 bo4 = *(const float4*)&bo[n];
#pragma unroll
    for (int msub = 0; msub < 4; ++msub) {
        const size_t g = (size_t)(m0 + msub * 16 + c) * 256 + n;
        const float4 r = *(const float4*)&x[g];
        float4 t;
        t.x = acc[msub][0] + bo4.x + r.x;
        t.y = acc[msub][1] + bo4.y + r.y;
        t.z = acc[msub][2] + bo4.z + r.z;
        t.w = acc[msub][3] + bo4.w + r.w;
        *(float4*)&out[g] = t;
    }
}

// ---------------------------------------------------------------------------
extern "C" void kernel_launch(void* const* d_in, const int* in_sizes, int n_in,
                              void* d_out, int out_size, void* d_ws, size_t ws_size,
                              hipStream_t stream)
{
    (void)in_sizes; (void)n_in; (void)out_size; (void)ws_size;
    const float* x   = (const float*)d_in[0];
    const float* lng = (const float*)d_in[1];
    const float* lnb = (const float*)d_in[2];
    const float* wq  = (const float*)d_in[3];
    const float* bq  = (const float*)d_in[4];
    const float* wk  = (const float*)d_in[5];
    const float* bk  = (const float*)d_in[6];
    const float* wv  = (const float*)d_in[7];
    const float* bv  = (const float*)d_in[8];
    const float* wo  = (const float*)d_in[9];
    const float* bo  = (const float*)d_in[10];
    const float* rb  = (const float*)d_in[11];
    // d_in[12] (rel_idx) unused: index recomputed analytically in-kernel.

    ushort_t* ws = (ushort_t*)d_ws;
    ushort_t* Xbf = ws;                       // 4194304 elems each
    ushort_t* Qbf = ws + 1 * 4194304;
    ushort_t* Kbf = ws + 2 * 4194304;
    ushort_t* Vbf = ws + 3 * 4194304;
    ushort_t* Obf = ws + 4 * 4194304;
    ushort_t* Wqb = ws + 5 * 4194304;
    ushort_t* Wkb = Wqb + 65536;
    ushort_t* Wvb = Wkb + 65536;
    ushort_t* Wob = Wvb + 65536;
    float* out = (float*)d_out;

    hipLaunchKernelGGL(prep_kernel,  dim3(768),  dim3(256), 0, stream,
                       x, lng, lnb, Xbf, wq, wk, wv, wo, Wqb, Wkb, Wvb, Wob);
    hipLaunchKernelGGL(qkv_kernel,   dim3(1024), dim3(256), 0, stream,
                       Xbf, Wqb, bq, Wkb, bk, Wvb, bv, Qbf, Kbf, Vbf);
    hipLaunchKernelGGL(attn_kernel,  dim3(1024), dim3(256), 0, stream, Qbf, Kbf, Vbf, rb, Obf);
    hipLaunchKernelGGL(oproj_kernel, dim3(1024), dim3(256), 0, stream, Obf, Wob, bo, x, out);
}

// Round 9
// 161.676 us; speedup vs baseline: 1.1013x; 1.0249x over previous
//
#include <hip/hip_runtime.h>
#include <cstdint>

#define PERB 262144   // C*H*H = N*D elements per batch
#define LOG2EF 1.4426950408889634f
#define C1F 0.09016844005556022f   // 0.0625 * log2(e)

typedef __attribute__((ext_vector_type(8))) short bf16x8;
typedef __attribute__((ext_vector_type(4))) float f32x4;
typedef unsigned short ushort_t;

__device__ __forceinline__ uint16_t f2bf(float f) {
    uint32_t u = __float_as_uint(f);
    u += 0x7fff + ((u >> 16) & 1);   // RNE
    return (uint16_t)(u >> 16);
}

// async global->LDS, 16B per lane. LDS dest is wave-uniform base (+lane*16 by HW);
// global src is per-lane.
__device__ __forceinline__ void glds16(const void* g, void* l) {
    __builtin_amdgcn_global_load_lds(
        (const __attribute__((address_space(1))) void*)g,
        (__attribute__((address_space(3))) void*)l, 16, 0, 0);
}

// ---------------------------------------------------------------------------
// Kernel 0: fused prep.
//   blocks [0,256)   : convert the 4 weight matrices (256x256 fp32) to bf16
//   blocks [256,512) : LayerNorm over channel axis -> bf16 X  (float4 loads,
//                      uint2 packed stores — round-9 vectorized rebuild)
//   blocks [512,520) : pre-scale rel-bias by log2(e) -> rb2 (saves a v_mul
//                      per P element in attn's exp chain)
// ---------------------------------------------------------------------------
__global__ __launch_bounds__(256) void prep_kernel(
    const float* __restrict__ x, const float* __restrict__ gam,
    const float* __restrict__ bet, ushort_t* __restrict__ X,
    const float* __restrict__ wq, const float* __restrict__ wk,
    const float* __restrict__ wv, const float* __restrict__ wo,
    ushort_t* __restrict__ oq, ushort_t* __restrict__ ok,
    ushort_t* __restrict__ ov, ushort_t* __restrict__ oo,
    const float* __restrict__ rb, float* __restrict__ rb2)
{
    const int blk = blockIdx.x;
    const int tid = threadIdx.x;
    if (blk < 256) {
        // ---- weight convert ----
        const int which = blk >> 6;
        const int idx = ((blk & 63) * 256 + tid) * 4;
        const float* src = which == 0 ? wq : which == 1 ? wk : which == 2 ? wv : wo;
        ushort_t* dst    = which == 0 ? oq : which == 1 ? ok : which == 2 ? ov : oo;
        const float4 v = *(const float4*)&src[idx];
        uint2 p;
        p.x = (uint32_t)f2bf(v.x) | ((uint32_t)f2bf(v.y) << 16);
        p.y = (uint32_t)f2bf(v.z) | ((uint32_t)f2bf(v.w) << 16);
        *(uint2*)&dst[idx] = p;
        return;
    }
    if (blk >= 512) {
        // ---- rel-bias pre-scale: rb2 = rb * log2(e) ----
        const int h = blk - 512;
        const float* s = rb + h * 3969;
        float* d = rb2 + h * 3969;
        for (int i = tid; i < 3969; i += 256) d[i] = s[i] * LOG2EF;
        return;
    }
    // ---- LayerNorm: block = (batch, 64 spatial); thread = (cg, v) ----
    const int lb  = blk - 256;            // 256 blocks
    const int b   = lb >> 4;              // 16 batches
    const int sp0 = (lb & 15) << 6;       // 16 spatial tiles of 64
    const int v   = tid & 15;             // 4 consecutive sp each
    const int cg  = tid >> 4;             // 16 channel groups of 16
    const int sp  = sp0 + v * 4;
    const float* xb = x + (size_t)b * PERB + sp;

    float4 vals[16];
    float4 s4 = {0.f, 0.f, 0.f, 0.f}, q4 = {0.f, 0.f, 0.f, 0.f};
#pragma unroll
    for (int i = 0; i < 16; ++i) {
        const float4 t = *(const float4*)&xb[(size_t)(cg * 16 + i) * 1024];
        vals[i] = t;
        s4.x += t.x; s4.y += t.y; s4.z += t.z; s4.w += t.w;
        q4.x += t.x * t.x; q4.y += t.y * t.y; q4.z += t.z * t.z; q4.w += t.w * t.w;
    }
    __shared__ float red[2][16][64];
    __shared__ float mr[2][64];
    *(float4*)&red[0][cg][v * 4] = s4;
    *(float4*)&red[1][cg][v * 4] = q4;
    __syncthreads();
    if (tid < 64) {
        float ts = 0.f, tq = 0.f;
#pragma unroll
        for (int g = 0; g < 16; ++g) { ts += red[0][g][tid]; tq += red[1][g][tid]; }
        const float mean = ts * (1.f / 256.f);
        const float var  = tq * (1.f / 256.f) - mean * mean;
        mr[0][tid] = mean;
        mr[1][tid] = rsqrtf(var + 1e-5f);
    }
    __syncthreads();
    const float4 mean4 = *(const float4*)&mr[0][v * 4];
    const float4 rstd4 = *(const float4*)&mr[1][v * 4];

    ushort_t* Xb = X + (size_t)b * PERB + sp;
#pragma unroll
    for (int i = 0; i < 16; ++i) {
        const int c = cg * 16 + i;
        const float g = gam[c], be = bet[c];
        const float4 t = vals[i];
        const float y0 = (t.x - mean4.x) * rstd4.x * g + be;
        const float y1 = (t.y - mean4.y) * rstd4.y * g + be;
        const float y2 = (t.z - mean4.z) * rstd4.z * g + be;
        const float y3 = (t.w - mean4.w) * rstd4.w * g + be;
        uint2 p;
        p.x = (uint32_t)f2bf(y0) | ((uint32_t)f2bf(y1) << 16);
        p.y = (uint32_t)f2bf(y2) | ((uint32_t)f2bf(y3) << 16);
        *(uint2*)&Xb[(size_t)c * 1024] = p;
    }
}

// ---------------------------------------------------------------------------
// Kernel 2: MFMA fused Q/K/V projection — exact round-3 form (best measured
// total). r8's counted-vmcnt variant was neutral-to-worse (sched_barrier
// pinning); the plain __syncthreads dbuf loop stays.
// ---------------------------------------------------------------------------
__device__ __forceinline__ void qkv_stage(
    ushort_t* Sb, const ushort_t* __restrict__ X,
    const ushort_t* __restrict__ wq, const ushort_t* __restrict__ wk,
    const ushort_t* __restrict__ wv,
    int m0, int n0, int k0, int w, int lane)
{
    const int rsub = lane >> 3;          // 0..7  row-within-8-group
    const int u    = lane & 7;           // 16B unit within 128B row
    const int koct = u ^ rsub;           // pre-swizzled global k-octet
#pragma unroll
    for (int i = 0; i < 2; ++i) {
        const int rg  = w * 2 + i;       // 8-row group 0..7
        const int row = rg * 8 + rsub;   // row&7 == rsub
        const int go  = k0 + koct * 8;
        ushort_t* db = Sb + rg * 512;    // wave-uniform dest base (+lane*16B by HW)
        glds16(&X [(size_t)(m0 + row) * 256 + go], db);
        glds16(&wq[(size_t)(n0 + row) * 256 + go], db + 4096);
        glds16(&wk[(size_t)(n0 + row) * 256 + go], db + 8192);
        glds16(&wv[(size_t)(n0 + row) * 256 + go], db + 12288);
    }
}

__device__ __forceinline__ void qkv_compute(
    const ushort_t* Sb, int w, int c, int quad, f32x4 acc[3][4])
{
#pragma unroll
    for (int ks = 0; ks < 2; ++ks) {
        const int kq = ks * 4 + quad;
        const int uo = (kq ^ (c & 7)) * 8;
        bf16x8 af[4];
#pragma unroll
        for (int msub = 0; msub < 4; ++msub)
            af[msub] = *(const bf16x8*)&Sb[(msub * 16 + c) * 64 + uo];
        bf16x8 bw[3];
#pragma unroll
        for (int o3 = 0; o3 < 3; ++o3)
            bw[o3] = *(const bf16x8*)&Sb[(o3 + 1) * 4096 + (w * 16 + c) * 64 + uo];
#pragma unroll
        for (int o3 = 0; o3 < 3; ++o3)
#pragma unroll
            for (int msub = 0; msub < 4; ++msub)
                acc[o3][msub] = __builtin_amdgcn_mfma_f32_16x16x32_bf16(
                    bw[o3], af[msub], acc[o3][msub], 0, 0, 0);
    }
}

__global__ __launch_bounds__(256) void qkv_kernel(
    const ushort_t* __restrict__ X,
    const ushort_t* __restrict__ wq, const float* __restrict__ bq,
    const ushort_t* __restrict__ wk, const float* __restrict__ bk,
    const ushort_t* __restrict__ wv, const float* __restrict__ bv,
    ushort_t* __restrict__ Q, ushort_t* __restrict__ K, ushort_t* __restrict__ V)
{
    __shared__ __align__(16) ushort_t SB0[4][4096];
    __shared__ __align__(16) ushort_t SB1[4][4096];

    const int blk = blockIdx.x;
    const int m0  = (blk >> 2) << 6;
    const int n0  = (blk & 3) << 6;
    const int tid = threadIdx.x;
    const int w    = tid >> 6;
    const int lane = tid & 63;
    const int quad = lane >> 4;
    const int c    = lane & 15;

    f32x4 acc[3][4];
#pragma unroll
    for (int o3 = 0; o3 < 3; ++o3)
#pragma unroll
        for (int i = 0; i < 4; ++i) acc[o3][i] = (f32x4){0.f, 0.f, 0.f, 0.f};

    qkv_stage(&SB0[0][0], X, wq, wk, wv, m0, n0, 0, w, lane);
    __syncthreads();
#pragma unroll
    for (int kc = 0; kc < 4; ++kc) {
        if (kc < 3) {
            if ((kc & 1) == 0)
                qkv_stage(&SB1[0][0], X, wq, wk, wv, m0, n0, (kc + 1) << 6, w, lane);
            else
                qkv_stage(&SB0[0][0], X, wq, wk, wv, m0, n0, (kc + 1) << 6, w, lane);
        }
        if ((kc & 1) == 0) qkv_compute(&SB0[0][0], w, c, quad, acc);
        else               qkv_compute(&SB1[0][0], w, c, quad, acc);
        __syncthreads();
    }

    const int n = n0 + w * 16 + quad * 4;
    const float4 bq4 = *(const float4*)&bq[n];
    const float4 bk4 = *(const float4*)&bk[n];
    const float4 bv4 = *(const float4*)&bv[n];
    ushort_t* outs[3] = {Q, K, V};
    const float4 bias[3] = {bq4, bk4, bv4};
#pragma unroll
    for (int msub = 0; msub < 4; ++msub) {
        const size_t m = (size_t)(m0 + msub * 16 + c);
#pragma unroll
        for (int o3 = 0; o3 < 3; ++o3) {
            const f32x4 a = acc[o3][msub];
            uint2 p;
            p.x = (uint32_t)f2bf(a[0] + bias[o3].x) | ((uint32_t)f2bf(a[1] + bias[o3].y) << 16);
            p.y = (uint32_t)f2bf(a[2] + bias[o3].z) | ((uint32_t)f2bf(a[3] + bias[o3].w) << 16);
            *(uint2*)&outs[o3][m * 256 + n] = p;
        }
    }
}

// ---------------------------------------------------------------------------
// Kernel 3: MFMA flash attention — round-0 structure (best measured 47.2us)
// with one change: bias read from the pre-scaled rb2 table, so the exp chain
// is fma(sacc, C1F, bias') + exp2 (drops 512 v_mul per thread, the busiest
// pipe being VALU/TRANS at 48%).
// ---------------------------------------------------------------------------
__global__ __launch_bounds__(256, 4) void attn_kernel(
    const ushort_t* __restrict__ Q, const ushort_t* __restrict__ K,
    const ushort_t* __restrict__ V, const float* __restrict__ relb2,
    ushort_t* __restrict__ O)
{
    // LDS map (bytes):
    //   [0, 16384)       P: 128 rows x 128B, 16B-unit swizzle; Q staging at start
    //   [16384, 20480)   K: granule (q=s>>3)*1024 + nn*16
    //   [20480, 28672)   V dbuf: buf*4096 + s*128, 16B-unit swizzle ^(s&7)
    __shared__ __align__(16) unsigned char smem[28672];
    char* Pb = (char*)smem;
    char* Kl = (char*)(smem + 16384);
    char* Vl = (char*)(smem + 20480);

    const int blk = blockIdx.x;
    const int bh  = blk & 127;
    const int mt  = blk >> 7;
    const int b   = bh >> 3;
    const int h   = bh & 7;
    const int m0  = mt << 7;
    const int tid = threadIdx.x;
    const int w    = tid >> 6;
    const int lane = tid & 63;
    const int quad = lane >> 4;
    const int c    = lane & 15;

    const size_t base = (size_t)b * PERB + (size_t)h * 32768;
    const ushort_t* Qg = Q + base;
    const ushort_t* Kg = K + base;
    const ushort_t* Vg = V + base;
    const float* rbh = relb2 + h * 3969;

    // ---- stage Q [32s x 128m] into Pb (granule layout), then read frags ----
    {
        const int mm = tid & 127;
        const int sg = tid >> 7;
        union { bf16x8 v; uint16_t u[8]; } g0, g1;
#pragma unroll
        for (int j = 0; j < 8; ++j)
            g0.u[j] = Qg[(size_t)(sg * 16 + j) * 1024 + m0 + mm];
#pragma unroll
        for (int j = 0; j < 8; ++j)
            g1.u[j] = Qg[(size_t)(sg * 16 + 8 + j) * 1024 + m0 + mm];
        *(bf16x8*)(Pb + (sg * 2 + 0) * 2048 + mm * 16) = g0.v;
        *(bf16x8*)(Pb + (sg * 2 + 1) * 2048 + mm * 16) = g1.v;
    }
    __syncthreads();
    bf16x8 qfrag[8];
#pragma unroll
    for (int msub = 0; msub < 8; ++msub)
        qfrag[msub] = *(const bf16x8*)(Pb + quad * 2048 + (msub * 16 + c) * 16);

    // per-msub bias m-offset: idx = noff(n) + moff(m)
    int moff[8];
#pragma unroll
    for (int msub = 0; msub < 8; ++msub) {
        const int m = m0 + msub * 16 + c;
        moff[msub] = 1984 - (m >> 5) * 63 - (m & 31);
    }

    // accumulators
    f32x4 oacc[2][2], dacc[2];
#pragma unroll
    for (int i = 0; i < 2; ++i) {
        dacc[i] = (f32x4){0.f, 0.f, 0.f, 0.f};
#pragma unroll
        for (int j = 0; j < 2; ++j) oacc[i][j] = (f32x4){0.f, 0.f, 0.f, 0.f};
    }
    bf16x8 onesf;
#pragma unroll
    for (int j = 0; j < 8; ++j) onesf[j] = (short)0x3F80;

    // staging thread coords + hoisted LDS addresses
    const int knn = tid & 63, ksg = tid >> 6;   // K: 8 s-values for column knn
    const int vs  = tid >> 3, vng = tid & 7;    // V: unit16 vng of row vs
    const int kWr = ksg * 1024 + knn * 16;
    const int vWr = vs * 128 + ((vng ^ (vs & 7)) << 4);
    const int kRd = quad * 1024 + (w * 16 + c) * 16;
    const int pWr = c * 128 + (((2 * w + (quad >> 1)) ^ (c & 7)) << 4) + ((quad & 1) << 3);
    const int c7  = c & 7;

    // prologue: prefetch chunk 0
    uint32_t kpre[8]; bf16x8 vpre;
#pragma unroll
    for (int j = 0; j < 8; ++j) kpre[j] = Kg[(size_t)(ksg * 8 + j) * 1024 + knn];
    vpre = *(const bf16x8*)&Vg[(size_t)vs * 1024 + vng * 8];

    for (int ch = 0; ch < 16; ++ch) {
        const int n0c = ch << 6;
        const int cb  = ch & 1;

        // ---- write prefetched K/V to LDS ----
        {
            uint4 kp;
            kp.x = kpre[0] | (kpre[1] << 16);
            kp.y = kpre[2] | (kpre[3] << 16);
            kp.z = kpre[4] | (kpre[5] << 16);
            kp.w = kpre[6] | (kpre[7] << 16);
            *(uint4*)(Kl + kWr) = kp;
            *(bf16x8*)(Vl + cb * 4096 + vWr) = vpre;
        }
        __syncthreads();   // staging visible; prev PV done for all waves

        // ---- prefetch next chunk into regs (overlaps S phase) ----
        {
            const int n0n = ((ch + 1) & 15) << 6;
#pragma unroll
            for (int j = 0; j < 8; ++j)
                kpre[j] = Kg[(size_t)(ksg * 8 + j) * 1024 + n0n + knn];
            vpre = *(const bf16x8*)&Vg[(size_t)vs * 1024 + n0n + vng * 8];
        }

        // ---- S phase ----
        const bf16x8 kf = *(const bf16x8*)(Kl + kRd);
        f32x4 sacc[8];
#pragma unroll
        for (int msub = 0; msub < 8; ++msub) {
            const f32x4 z = {0.f, 0.f, 0.f, 0.f};
            sacc[msub] = __builtin_amdgcn_mfma_f32_16x16x32_bf16(kf, qfrag[msub], z, 0, 0, 0);
        }

        // ---- bias (pre-scaled, L1/L2-hit) + exp2 + trunc-pack + P write ----
        const int nbase = n0c + w * 16 + quad * 4;
        const int nidx0 = (nbase >> 5) * 63 + (nbase & 31);  // 4 consecutive ints follow
#pragma unroll
        for (int msub = 0; msub < 8; ++msub) {
            const float* bp = rbh + nidx0 + moff[msub];
            float p[4];
#pragma unroll
            for (int r = 0; r < 4; ++r)
                p[r] = __builtin_amdgcn_exp2f(fmaf(sacc[msub][r], C1F, bp[r]));
            uint2 pk;
            pk.x = __builtin_amdgcn_perm(__float_as_uint(p[1]), __float_as_uint(p[0]), 0x07060302u);
            pk.y = __builtin_amdgcn_perm(__float_as_uint(p[3]), __float_as_uint(p[2]), 0x07060302u);
            *(uint2*)(Pb + msub * 2048 + pWr) = pk;
        }
        __syncthreads();   // P (and V) ready for PV

        // ---- PV phase: wave w owns msub {2w, 2w+1} ----
#pragma unroll
        for (int kstep = 0; kstep < 2; ++kstep) {
            const int u = ((kstep * 4 + quad) ^ c7) << 4;
            const bf16x8 vf0 = *(const bf16x8*)(Vl + cb * 4096 + c * 128 + u);
            const bf16x8 vf1 = *(const bf16x8*)(Vl + cb * 4096 + (16 + c) * 128 + u);
#pragma unroll
            for (int mi = 0; mi < 2; ++mi) {
                const bf16x8 pf = *(const bf16x8*)(Pb + ((w * 2 + mi) * 16 + c) * 128 + u);
                oacc[0][mi] = __builtin_amdgcn_mfma_f32_16x16x32_bf16(vf0, pf, oacc[0][mi], 0, 0, 0);
                oacc[1][mi] = __builtin_amdgcn_mfma_f32_16x16x32_bf16(vf1, pf, oacc[1][mi], 0, 0, 0);
                dacc[mi]    = __builtin_amdgcn_mfma_f32_16x16x32_bf16(onesf, pf, dacc[mi], 0, 0, 0);
            }
        }
    }

    // ---- epilogue: scale by 1/denominator, write O ----
    ushort_t* Ob = O + base;
#pragma unroll
    for (int mi = 0; mi < 2; ++mi) {
        const float inv = 1.0f / dacc[mi][0];
        const int m = m0 + (w * 2 + mi) * 16 + c;
#pragma unroll
        for (int ssub = 0; ssub < 2; ++ssub)
#pragma unroll
            for (int r = 0; r < 4; ++r)
                Ob[(size_t)(ssub * 16 + quad * 4 + r) * 1024 + m] = f2bf(oacc[ssub][mi][r] * inv);
    }
}

// ---------------------------------------------------------------------------
// Kernel 4: MFMA output projection + bias + residual — exact round-3 form.
// ---------------------------------------------------------------------------
__device__ __forceinline__ void oproj_stage(
    ushort_t* Sb, const ushort_t* __restrict__ A, const ushort_t* __restrict__ wo,
    int m0, int n0, int k0, int w, int lane)
{
    const int rsub = lane >> 3;
    const int u    = lane & 7;
    const int koct = u ^ rsub;
#pragma unroll
    for (int i = 0; i < 2; ++i) {
        const int rg  = w * 2 + i;
        const int row = rg * 8 + rsub;
        const int go  = k0 + koct * 8;
        ushort_t* db = Sb + rg * 512;
        glds16(&A [(size_t)(m0 + row) * 256 + go], db);
        glds16(&wo[(size_t)(n0 + row) * 256 + go], db + 4096);
    }
}

__device__ __forceinline__ void oproj_compute(
    const ushort_t* Sb, int w, int c, int quad, f32x4 acc[4])
{
#pragma unroll
    for (int ks = 0; ks < 2; ++ks) {
        const int kq = ks * 4 + quad;
        const int uo = (kq ^ (c & 7)) * 8;
        const bf16x8 bw = *(const bf16x8*)&Sb[4096 + (w * 16 + c) * 64 + uo];
#pragma unroll
        for (int msub = 0; msub < 4; ++msub) {
            const bf16x8 af = *(const bf16x8*)&Sb[(msub * 16 + c) * 64 + uo];
            acc[msub] = __builtin_amdgcn_mfma_f32_16x16x32_bf16(bw, af, acc[msub], 0, 0, 0);
        }
    }
}

__global__ __launch_bounds__(256, 4) void oproj_kernel(
    const ushort_t* __restrict__ A, const ushort_t* __restrict__ wo,
    const float* __restrict__ bo, const float* __restrict__ x,
    float* __restrict__ out)
{
    __shared__ __align__(16) ushort_t SA0[2][4096];
    __shared__ __align__(16) ushort_t SA1[2][4096];

    const int blk = blockIdx.x;
    const int m0  = (blk >> 2) << 6;
    const int n0  = (blk & 3) << 6;
    const int tid = threadIdx.x;
    const int w    = tid >> 6;
    const int lane = tid & 63;
    const int quad = lane >> 4;
    const int c    = lane & 15;

    f32x4 acc[4];
#pragma unroll
    for (int i = 0; i < 4; ++i) acc[i] = (f32x4){0.f, 0.f, 0.f, 0.f};

    oproj_stage(&SA0[0][0], A, wo, m0, n0, 0, w, lane);
    __syncthreads();
#pragma unroll
    for (int kc = 0; kc < 4; ++kc) {
        if (kc < 3) {
            if ((kc & 1) == 0)
                oproj_stage(&SA1[0][0], A, wo, m0, n0, (kc + 1) << 6, w, lane);
            else
                oproj_stage(&SA0[0][0], A, wo, m0, n0, (kc + 1) << 6, w, lane);
        }
        if ((kc & 1) == 0) oproj_compute(&SA0[0][0], w, c, quad, acc);
        else               oproj_compute(&SA1[0][0], w, c, quad, acc);
        __syncthreads();
    }

    const int n = n0 + w * 16 + quad * 4;
    const float4 bo4 = *(const float4*)&bo[n];
#pragma unroll
    for (int msub = 0; msub < 4; ++msub) {
        const size_t g = (size_t)(m0 + msub * 16 + c) * 256 + n;
        const float4 r = *(const float4*)&x[g];
        float4 t;
        t.x = acc[msub][0] + bo4.x + r.x;
        t.y = acc[msub][1] + bo4.y + r.y;
        t.z = acc[msub][2] + bo4.z + r.z;
        t.w = acc[msub][3] + bo4.w + r.w;
        *(float4*)&out[g] = t;
    }
}

// ---------------------------------------------------------------------------
extern "C" void kernel_launch(void* const* d_in, const int* in_sizes, int n_in,
                              void* d_out, int out_size, void* d_ws, size_t ws_size,
                              hipStream_t stream)
{
    (void)in_sizes; (void)n_in; (void)out_size; (void)ws_size;
    const float* x   = (const float*)d_in[0];
    const float* lng = (const float*)d_in[1];
    const float* lnb = (const float*)d_in[2];
    const float* wq  = (const float*)d_in[3];
    const float* bq  = (const float*)d_in[4];
    const float* wk  = (const float*)d_in[5];
    const float* bk  = (const float*)d_in[6];
    const float* wv  = (const float*)d_in[7];
    const float* bv  = (const float*)d_in[8];
    const float* wo  = (const float*)d_in[9];
    const float* bo  = (const float*)d_in[10];
    const float* rb  = (const float*)d_in[11];
    // d_in[12] (rel_idx) unused: index recomputed analytically in-kernel.

    ushort_t* ws = (ushort_t*)d_ws;
    ushort_t* Xbf = ws;                       // 4194304 elems each
    ushort_t* Qbf = ws + 1 * 4194304;
    ushort_t* Kbf = ws + 2 * 4194304;
    ushort_t* Vbf = ws + 3 * 4194304;
    ushort_t* Obf = ws + 4 * 4194304;
    ushort_t* Wqb = ws + 5 * 4194304;
    ushort_t* Wkb = Wqb + 65536;
    ushort_t* Wvb = Wkb + 65536;
    ushort_t* Wob = Wvb + 65536;
    float* rb2 = (float*)(Wob + 65536);       // 31752 floats, 4B-aligned
    float* out = (float*)d_out;

    hipLaunchKernelGGL(prep_kernel,  dim3(520),  dim3(256), 0, stream,
                       x, lng, lnb, Xbf, wq, wk, wv, wo, Wqb, Wkb, Wvb, Wob, rb, rb2);
    hipLaunchKernelGGL(qkv_kernel,   dim3(1024), dim3(256), 0, stream,
                       Xbf, Wqb, bq, Wkb, bk, Wvb, bv, Qbf, Kbf, Vbf);
    hipLaunchKernelGGL(attn_kernel,  dim3(1024), dim3(256), 0, stream, Qbf, Kbf, Vbf, rb2, Obf);
    hipLaunchKernelGGL(oproj_kernel, dim3(1024), dim3(256), 0, stream, Obf, Wob, bo, x, out);
}

// Round 10
// 156.342 us; speedup vs baseline: 1.1388x; 1.0341x over previous
//
#include <hip/hip_runtime.h>
#include <cstdint>

#define PERB 262144   // C*H*H = N*D elements per batch
#define LOG2EF 1.4426950408889634f
#define C1F 0.09016844005556022f   // 0.0625 * log2(e)

typedef __attribute__((ext_vector_type(8))) short bf16x8;
typedef __attribute__((ext_vector_type(4))) float f32x4;
typedef unsigned short ushort_t;

__device__ __forceinline__ uint16_t f2bf(float f) {
    uint32_t u = __float_as_uint(f);
    u += 0x7fff + ((u >> 16) & 1);   // RNE
    return (uint16_t)(u >> 16);
}

// async global->LDS, 16B per lane. LDS dest is wave-uniform base (+lane*16 by HW);
// global src is per-lane.
__device__ __forceinline__ void glds16(const void* g, void* l) {
    __builtin_amdgcn_global_load_lds(
        (const __attribute__((address_space(1))) void*)g,
        (__attribute__((address_space(3))) void*)l, 16, 0, 0);
}

// ---------------------------------------------------------------------------
// Kernel 0: fused prep (round-9 form).
//   blocks [0,256)   : convert the 4 weight matrices (256x256 fp32) to bf16
//   blocks [256,512) : LayerNorm over channel axis -> bf16 X (float4 loads)
//   blocks [512,520) : pre-scale rel-bias by log2(e) -> rb2
// ---------------------------------------------------------------------------
__global__ __launch_bounds__(256) void prep_kernel(
    const float* __restrict__ x, const float* __restrict__ gam,
    const float* __restrict__ bet, ushort_t* __restrict__ X,
    const float* __restrict__ wq, const float* __restrict__ wk,
    const float* __restrict__ wv, const float* __restrict__ wo,
    ushort_t* __restrict__ oq, ushort_t* __restrict__ ok,
    ushort_t* __restrict__ ov, ushort_t* __restrict__ oo,
    const float* __restrict__ rb, float* __restrict__ rb2)
{
    const int blk = blockIdx.x;
    const int tid = threadIdx.x;
    if (blk < 256) {
        const int which = blk >> 6;
        const int idx = ((blk & 63) * 256 + tid) * 4;
        const float* src = which == 0 ? wq : which == 1 ? wk : which == 2 ? wv : wo;
        ushort_t* dst    = which == 0 ? oq : which == 1 ? ok : which == 2 ? ov : oo;
        const float4 v = *(const float4*)&src[idx];
        uint2 p;
        p.x = (uint32_t)f2bf(v.x) | ((uint32_t)f2bf(v.y) << 16);
        p.y = (uint32_t)f2bf(v.z) | ((uint32_t)f2bf(v.w) << 16);
        *(uint2*)&dst[idx] = p;
        return;
    }
    if (blk >= 512) {
        const int h = blk - 512;
        const float* s = rb + h * 3969;
        float* d = rb2 + h * 3969;
        for (int i = tid; i < 3969; i += 256) d[i] = s[i] * LOG2EF;
        return;
    }
    const int lb  = blk - 256;            // 256 blocks
    const int b   = lb >> 4;              // 16 batches
    const int sp0 = (lb & 15) << 6;       // 16 spatial tiles of 64
    const int v   = tid & 15;             // 4 consecutive sp each
    const int cg  = tid >> 4;             // 16 channel groups of 16
    const int sp  = sp0 + v * 4;
    const float* xb = x + (size_t)b * PERB + sp;

    float4 vals[16];
    float4 s4 = {0.f, 0.f, 0.f, 0.f}, q4 = {0.f, 0.f, 0.f, 0.f};
#pragma unroll
    for (int i = 0; i < 16; ++i) {
        const float4 t = *(const float4*)&xb[(size_t)(cg * 16 + i) * 1024];
        vals[i] = t;
        s4.x += t.x; s4.y += t.y; s4.z += t.z; s4.w += t.w;
        q4.x += t.x * t.x; q4.y += t.y * t.y; q4.z += t.z * t.z; q4.w += t.w * t.w;
    }
    __shared__ float red[2][16][64];
    __shared__ float mr[2][64];
    *(float4*)&red[0][cg][v * 4] = s4;
    *(float4*)&red[1][cg][v * 4] = q4;
    __syncthreads();
    if (tid < 64) {
        float ts = 0.f, tq = 0.f;
#pragma unroll
        for (int g = 0; g < 16; ++g) { ts += red[0][g][tid]; tq += red[1][g][tid]; }
        const float mean = ts * (1.f / 256.f);
        const float var  = tq * (1.f / 256.f) - mean * mean;
        mr[0][tid] = mean;
        mr[1][tid] = rsqrtf(var + 1e-5f);
    }
    __syncthreads();
    const float4 mean4 = *(const float4*)&mr[0][v * 4];
    const float4 rstd4 = *(const float4*)&mr[1][v * 4];

    ushort_t* Xb = X + (size_t)b * PERB + sp;
#pragma unroll
    for (int i = 0; i < 16; ++i) {
        const int c = cg * 16 + i;
        const float g = gam[c], be = bet[c];
        const float4 t = vals[i];
        const float y0 = (t.x - mean4.x) * rstd4.x * g + be;
        const float y1 = (t.y - mean4.y) * rstd4.y * g + be;
        const float y2 = (t.z - mean4.z) * rstd4.z * g + be;
        const float y3 = (t.w - mean4.w) * rstd4.w * g + be;
        uint2 p;
        p.x = (uint32_t)f2bf(y0) | ((uint32_t)f2bf(y1) << 16);
        p.y = (uint32_t)f2bf(y2) | ((uint32_t)f2bf(y3) << 16);
        *(uint2*)&Xb[(size_t)c * 1024] = p;
    }
}

// ---------------------------------------------------------------------------
// Kernel 2: MFMA fused Q/K/V projection — exact round-3 form (best measured).
// ---------------------------------------------------------------------------
__device__ __forceinline__ void qkv_stage(
    ushort_t* Sb, const ushort_t* __restrict__ X,
    const ushort_t* __restrict__ wq, const ushort_t* __restrict__ wk,
    const ushort_t* __restrict__ wv,
    int m0, int n0, int k0, int w, int lane)
{
    const int rsub = lane >> 3;          // 0..7  row-within-8-group
    const int u    = lane & 7;           // 16B unit within 128B row
    const int koct = u ^ rsub;           // pre-swizzled global k-octet
#pragma unroll
    for (int i = 0; i < 2; ++i) {
        const int rg  = w * 2 + i;       // 8-row group 0..7
        const int row = rg * 8 + rsub;   // row&7 == rsub
        const int go  = k0 + koct * 8;
        ushort_t* db = Sb + rg * 512;    // wave-uniform dest base (+lane*16B by HW)
        glds16(&X [(size_t)(m0 + row) * 256 + go], db);
        glds16(&wq[(size_t)(n0 + row) * 256 + go], db + 4096);
        glds16(&wk[(size_t)(n0 + row) * 256 + go], db + 8192);
        glds16(&wv[(size_t)(n0 + row) * 256 + go], db + 12288);
    }
}

__device__ __forceinline__ void qkv_compute(
    const ushort_t* Sb, int w, int c, int quad, f32x4 acc[3][4])
{
#pragma unroll
    for (int ks = 0; ks < 2; ++ks) {
        const int kq = ks * 4 + quad;
        const int uo = (kq ^ (c & 7)) * 8;
        bf16x8 af[4];
#pragma unroll
        for (int msub = 0; msub < 4; ++msub)
            af[msub] = *(const bf16x8*)&Sb[(msub * 16 + c) * 64 + uo];
        bf16x8 bw[3];
#pragma unroll
        for (int o3 = 0; o3 < 3; ++o3)
            bw[o3] = *(const bf16x8*)&Sb[(o3 + 1) * 4096 + (w * 16 + c) * 64 + uo];
#pragma unroll
        for (int o3 = 0; o3 < 3; ++o3)
#pragma unroll
            for (int msub = 0; msub < 4; ++msub)
                acc[o3][msub] = __builtin_amdgcn_mfma_f32_16x16x32_bf16(
                    bw[o3], af[msub], acc[o3][msub], 0, 0, 0);
    }
}

__global__ __launch_bounds__(256) void qkv_kernel(
    const ushort_t* __restrict__ X,
    const ushort_t* __restrict__ wq, const float* __restrict__ bq,
    const ushort_t* __restrict__ wk, const float* __restrict__ bk,
    const ushort_t* __restrict__ wv, const float* __restrict__ bv,
    ushort_t* __restrict__ Q, ushort_t* __restrict__ K, ushort_t* __restrict__ V)
{
    __shared__ __align__(16) ushort_t SB0[4][4096];
    __shared__ __align__(16) ushort_t SB1[4][4096];

    const int blk = blockIdx.x;
    const int m0  = (blk >> 2) << 6;
    const int n0  = (blk & 3) << 6;
    const int tid = threadIdx.x;
    const int w    = tid >> 6;
    const int lane = tid & 63;
    const int quad = lane >> 4;
    const int c    = lane & 15;

    f32x4 acc[3][4];
#pragma unroll
    for (int o3 = 0; o3 < 3; ++o3)
#pragma unroll
        for (int i = 0; i < 4; ++i) acc[o3][i] = (f32x4){0.f, 0.f, 0.f, 0.f};

    qkv_stage(&SB0[0][0], X, wq, wk, wv, m0, n0, 0, w, lane);
    __syncthreads();
#pragma unroll
    for (int kc = 0; kc < 4; ++kc) {
        if (kc < 3) {
            if ((kc & 1) == 0)
                qkv_stage(&SB1[0][0], X, wq, wk, wv, m0, n0, (kc + 1) << 6, w, lane);
            else
                qkv_stage(&SB0[0][0], X, wq, wk, wv, m0, n0, (kc + 1) << 6, w, lane);
        }
        if ((kc & 1) == 0) qkv_compute(&SB0[0][0], w, c, quad, acc);
        else               qkv_compute(&SB1[0][0], w, c, quad, acc);
        __syncthreads();
    }

    const int n = n0 + w * 16 + quad * 4;
    const float4 bq4 = *(const float4*)&bq[n];
    const float4 bk4 = *(const float4*)&bk[n];
    const float4 bv4 = *(const float4*)&bv[n];
    ushort_t* outs[3] = {Q, K, V};
    const float4 bias[3] = {bq4, bk4, bv4};
#pragma unroll
    for (int msub = 0; msub < 4; ++msub) {
        const size_t m = (size_t)(m0 + msub * 16 + c);
#pragma unroll
        for (int o3 = 0; o3 < 3; ++o3) {
            const f32x4 a = acc[o3][msub];
            uint2 p;
            p.x = (uint32_t)f2bf(a[0] + bias[o3].x) | ((uint32_t)f2bf(a[1] + bias[o3].y) << 16);
            p.y = (uint32_t)f2bf(a[2] + bias[o3].z) | ((uint32_t)f2bf(a[3] + bias[o3].w) << 16);
            *(uint2*)&outs[o3][m * 256 + n] = p;
        }
    }
}

// ---------------------------------------------------------------------------
// Kernel 3: MFMA flash attention, round-16: ONE barrier per chunk.
//  Work split transposed: wave w computes S for its OWN 32 m-rows x all 64 n
//  (kf[4], qfrag[2]) so P rows [w*32, w*32+32) are written AND read by the
//  same wave — the P-write->PV dependency becomes in-wave lgkmcnt and
//  barrier B disappears (16 barriers/block vs 32). K now double-buffered
//  (+4KB; LDS = 32768 exactly, still 4 blocks/CU). K/V reg-prefetch issued a
//  full chunk ahead. Hazards: buf[cb] reads vs buf[cb^1] writes separated by
//  the single barrier (drift < 1 interval); P wave-private; extra prologue
//  barrier orders qfrag reads before first P writes.
// ---------------------------------------------------------------------------
__global__ __launch_bounds__(256, 4) void attn_kernel(
    const ushort_t* __restrict__ Q, const ushort_t* __restrict__ K,
    const ushort_t* __restrict__ V, const float* __restrict__ relb2,
    ushort_t* __restrict__ O)
{
    // LDS map (bytes):
    //   [0, 16384)       P: 128 rows x 128B, wave-private rows; Q staging at start
    //   [16384, 24576)   K dbuf: buf*4096 + (s>>3)*1024 + tok*16
    //   [24576, 32768)   V dbuf: buf*4096 + d*128, 16B-unit swizzle ^(d&7)
    __shared__ __align__(16) unsigned char smem[32768];
    char* Pb = (char*)smem;
    char* Kl = (char*)(smem + 16384);
    char* Vl = (char*)(smem + 24576);

    const int blk = blockIdx.x;
    const int bh  = blk & 127;
    const int mt  = blk >> 7;
    const int b   = bh >> 3;
    const int h   = bh & 7;
    const int m0  = mt << 7;
    const int tid = threadIdx.x;
    const int w    = tid >> 6;
    const int lane = tid & 63;
    const int quad = lane >> 4;
    const int c    = lane & 15;

    const size_t base = (size_t)b * PERB + (size_t)h * 32768;
    const ushort_t* Qg = Q + base;
    const ushort_t* Kg = K + base;
    const ushort_t* Vg = V + base;
    const float* rbh = relb2 + h * 3969;

    // staging thread coords + hoisted LDS addresses
    const int knn = tid & 63, ksg = tid >> 6;   // K: 8 s-values for column knn
    const int vs  = tid >> 3, vng = tid & 7;    // V: unit16 vng of row vs
    const int kWr = ksg * 1024 + knn * 16;
    const int vWr = vs * 128 + ((vng ^ (vs & 7)) << 4);
    const int c7  = c & 7;

    // ---- prologue: load chunk 0 into regs ----
    uint32_t kpre[8]; bf16x8 vpre;
#pragma unroll
    for (int j = 0; j < 8; ++j) kpre[j] = Kg[(size_t)(ksg * 8 + j) * 1024 + knn];
    vpre = *(const bf16x8*)&Vg[(size_t)vs * 1024 + vng * 8];

    // ---- stage Q [32s x 128m] into Pb (granule layout) ----
    {
        const int mm = tid & 127;
        const int sg = tid >> 7;
        union { bf16x8 v; uint16_t u[8]; } g0, g1;
#pragma unroll
        for (int j = 0; j < 8; ++j)
            g0.u[j] = Qg[(size_t)(sg * 16 + j) * 1024 + m0 + mm];
#pragma unroll
        for (int j = 0; j < 8; ++j)
            g1.u[j] = Qg[(size_t)(sg * 16 + 8 + j) * 1024 + m0 + mm];
        *(bf16x8*)(Pb + (sg * 2 + 0) * 2048 + mm * 16) = g0.v;
        *(bf16x8*)(Pb + (sg * 2 + 1) * 2048 + mm * 16) = g1.v;
    }
    // ---- write chunk-0 K/V into buf 0 ----
    {
        uint4 kp;
        kp.x = kpre[0] | (kpre[1] << 16);
        kp.y = kpre[2] | (kpre[3] << 16);
        kp.z = kpre[4] | (kpre[5] << 16);
        kp.w = kpre[6] | (kpre[7] << 16);
        *(uint4*)(Kl + kWr) = kp;
        *(bf16x8*)(Vl + vWr) = vpre;
    }
    __syncthreads();   // Q + chunk-0 staging visible

    // ---- read own Q fragments (rows 2w, 2w+1) ----
    bf16x8 qfrag[2];
#pragma unroll
    for (int mi = 0; mi < 2; ++mi)
        qfrag[mi] = *(const bf16x8*)(Pb + quad * 2048 + (((w * 2 + mi) * 16 + c)) * 16);
    __syncthreads();   // all qfrag reads done before any wave's first P write

    // bias m-offsets for own rows
    int moff[2];
#pragma unroll
    for (int mi = 0; mi < 2; ++mi) {
        const int m = m0 + (w * 2 + mi) * 16 + c;
        moff[mi] = 1984 - (m >> 5) * 63 - (m & 31);
    }
    const int rowb0 = ((w * 2 + 0) * 16 + c) * 128;
    const int rowb1 = ((w * 2 + 1) * 16 + c) * 128;

    // accumulators
    f32x4 oacc[2][2], dacc[2];
#pragma unroll
    for (int i = 0; i < 2; ++i) {
        dacc[i] = (f32x4){0.f, 0.f, 0.f, 0.f};
#pragma unroll
        for (int j = 0; j < 2; ++j) oacc[i][j] = (f32x4){0.f, 0.f, 0.f, 0.f};
    }
    bf16x8 onesf;
#pragma unroll
    for (int j = 0; j < 8; ++j) onesf[j] = (short)0x3F80;

    // ---- load chunk-1 regs (written at end of iter 0) ----
#pragma unroll
    for (int j = 0; j < 8; ++j) kpre[j] = Kg[(size_t)(ksg * 8 + j) * 1024 + 64 + knn];
    vpre = *(const bf16x8*)&Vg[(size_t)vs * 1024 + 64 + vng * 8];

    for (int ch = 0; ch < 16; ++ch) {
        const int n0c = ch << 6;
        const int cb  = ch & 1;
        const char* Kc = Kl + (cb << 12);
        const char* Vc = Vl + (cb << 12);

        // ---- S phase: own 32 m-rows x all 64 n ----
        bf16x8 kf[4];
#pragma unroll
        for (int nsub = 0; nsub < 4; ++nsub)
            kf[nsub] = *(const bf16x8*)(Kc + quad * 1024 + (nsub * 16 + c) * 16);
        f32x4 sacc[2][4];
#pragma unroll
        for (int mi = 0; mi < 2; ++mi)
#pragma unroll
            for (int nsub = 0; nsub < 4; ++nsub) {
                const f32x4 z = {0.f, 0.f, 0.f, 0.f};
                sacc[mi][nsub] = __builtin_amdgcn_mfma_f32_16x16x32_bf16(
                    kf[nsub], qfrag[mi], z, 0, 0, 0);
            }

        // ---- bias + exp2 + pack + P write (own rows only) ----
#pragma unroll
        for (int mi = 0; mi < 2; ++mi) {
            const int rowb = mi ? rowb1 : rowb0;
#pragma unroll
            for (int nsub = 0; nsub < 4; ++nsub) {
                const int nbase = n0c + nsub * 16 + quad * 4;
                const int nidx0 = (nbase >> 5) * 63 + (nbase & 31);
                const float* bp = rbh + nidx0 + moff[mi];
                float p[4];
#pragma unroll
                for (int r = 0; r < 4; ++r)
                    p[r] = __builtin_amdgcn_exp2f(fmaf(sacc[mi][nsub][r], C1F, bp[r]));
                uint2 pk;
                pk.x = __builtin_amdgcn_perm(__float_as_uint(p[1]), __float_as_uint(p[0]), 0x07060302u);
                pk.y = __builtin_amdgcn_perm(__float_as_uint(p[3]), __float_as_uint(p[2]), 0x07060302u);
                const int u = (2 * nsub + (quad >> 1)) ^ c7;
                *(uint2*)(Pb + rowb + u * 16 + ((quad & 1) << 3)) = pk;
            }
        }

        // ---- PV phase: own P rows (in-wave lgkmcnt, no barrier) ----
#pragma unroll
        for (int kstep = 0; kstep < 2; ++kstep) {
            const int u = ((kstep * 4 + quad) ^ c7) << 4;
            const bf16x8 vf0 = *(const bf16x8*)(Vc + c * 128 + u);
            const bf16x8 vf1 = *(const bf16x8*)(Vc + (16 + c) * 128 + u);
#pragma unroll
            for (int mi = 0; mi < 2; ++mi) {
                const bf16x8 pf = *(const bf16x8*)(Pb + (mi ? rowb1 : rowb0) + u);
                oacc[0][mi] = __builtin_amdgcn_mfma_f32_16x16x32_bf16(vf0, pf, oacc[0][mi], 0, 0, 0);
                oacc[1][mi] = __builtin_amdgcn_mfma_f32_16x16x32_bf16(vf1, pf, oacc[1][mi], 0, 0, 0);
                dacc[mi]    = __builtin_amdgcn_mfma_f32_16x16x32_bf16(onesf, pf, dacc[mi], 0, 0, 0);
            }
        }

        // ---- stage next chunk into buf[cb^1]; load chunk ch+2 regs ----
        if (ch < 15) {
            const int nb = (cb ^ 1) << 12;
            uint4 kp;
            kp.x = kpre[0] | (kpre[1] << 16);
            kp.y = kpre[2] | (kpre[3] << 16);
            kp.z = kpre[4] | (kpre[5] << 16);
            kp.w = kpre[6] | (kpre[7] << 16);
            *(uint4*)(Kl + nb + kWr) = kp;
            *(bf16x8*)(Vl + nb + vWr) = vpre;
            if (ch < 14) {
                const int n0n = (ch + 2) << 6;
#pragma unroll
                for (int j = 0; j < 8; ++j)
                    kpre[j] = Kg[(size_t)(ksg * 8 + j) * 1024 + n0n + knn];
                vpre = *(const bf16x8*)&Vg[(size_t)vs * 1024 + n0n + vng * 8];
            }
        }
        __syncthreads();   // single barrier: next staging visible, buf roles flip
    }

    // ---- epilogue: scale by 1/denominator, write O ----
    ushort_t* Ob = O + base;
#pragma unroll
    for (int mi = 0; mi < 2; ++mi) {
        const float inv = 1.0f / dacc[mi][0];
        const int m = m0 + (w * 2 + mi) * 16 + c;
#pragma unroll
        for (int ssub = 0; ssub < 2; ++ssub)
#pragma unroll
            for (int r = 0; r < 4; ++r)
                Ob[(size_t)(ssub * 16 + quad * 4 + r) * 1024 + m] = f2bf(oacc[ssub][mi][r] * inv);
    }
}

// ---------------------------------------------------------------------------
// Kernel 4: MFMA output projection + bias + residual — exact round-3 form.
// ---------------------------------------------------------------------------
__device__ __forceinline__ void oproj_stage(
    ushort_t* Sb, const ushort_t* __restrict__ A, const ushort_t* __restrict__ wo,
    int m0, int n0, int k0, int w, int lane)
{
    const int rsub = lane >> 3;
    const int u    = lane & 7;
    const int koct = u ^ rsub;
#pragma unroll
    for (int i = 0; i < 2; ++i) {
        const int rg  = w * 2 + i;
        const int row = rg * 8 + rsub;
        const int go  = k0 + koct * 8;
        ushort_t* db = Sb + rg * 512;
        glds16(&A [(size_t)(m0 + row) * 256 + go], db);
        glds16(&wo[(size_t)(n0 + row) * 256 + go], db + 4096);
    }
}

__device__ __forceinline__ void oproj_compute(
    const ushort_t* Sb, int w, int c, int quad, f32x4 acc[4])
{
#pragma unroll
    for (int ks = 0; ks < 2; ++ks) {
        const int kq = ks * 4 + quad;
        const int uo = (kq ^ (c & 7)) * 8;
        const bf16x8 bw = *(const bf16x8*)&Sb[4096 + (w * 16 + c) * 64 + uo];
#pragma unroll
        for (int msub = 0; msub < 4; ++msub) {
            const bf16x8 af = *(const bf16x8*)&Sb[(msub * 16 + c) * 64 + uo];
            acc[msub] = __builtin_amdgcn_mfma_f32_16x16x32_bf16(bw, af, acc[msub], 0, 0, 0);
        }
    }
}

__global__ __launch_bounds__(256, 4) void oproj_kernel(
    const ushort_t* __restrict__ A, const ushort_t* __restrict__ wo,
    const float* __restrict__ bo, const float* __restrict__ x,
    float* __restrict__ out)
{
    __shared__ __align__(16) ushort_t SA0[2][4096];
    __shared__ __align__(16) ushort_t SA1[2][4096];

    const int blk = blockIdx.x;
    const int m0  = (blk >> 2) << 6;
    const int n0  = (blk & 3) << 6;
    const int tid = threadIdx.x;
    const int w    = tid >> 6;
    const int lane = tid & 63;
    const int quad = lane >> 4;
    const int c    = lane & 15;

    f32x4 acc[4];
#pragma unroll
    for (int i = 0; i < 4; ++i) acc[i] = (f32x4){0.f, 0.f, 0.f, 0.f};

    oproj_stage(&SA0[0][0], A, wo, m0, n0, 0, w, lane);
    __syncthreads();
#pragma unroll
    for (int kc = 0; kc < 4; ++kc) {
        if (kc < 3) {
            if ((kc & 1) == 0)
                oproj_stage(&SA1[0][0], A, wo, m0, n0, (kc + 1) << 6, w, lane);
            else
                oproj_stage(&SA0[0][0], A, wo, m0, n0, (kc + 1) << 6, w, lane);
        }
        if ((kc & 1) == 0) oproj_compute(&SA0[0][0], w, c, quad, acc);
        else               oproj_compute(&SA1[0][0], w, c, quad, acc);
        __syncthreads();
    }

    const int n = n0 + w * 16 + quad * 4;
    const float4 bo4 = *(const float4*)&bo[n];
#pragma unroll
    for (int msub = 0; msub < 4; ++msub) {
        const size_t g = (size_t)(m0 + msub * 16 + c) * 256 + n;
        const float4 r = *(const float4*)&x[g];
        float4 t;
        t.x = acc[msub][0] + bo4.x + r.x;
        t.y = acc[msub][1] + bo4.y + r.y;
        t.z = acc[msub][2] + bo4.z + r.z;
        t.w = acc[msub][3] + bo4.w + r.w;
        *(float4*)&out[g] = t;
    }
}

// ---------------------------------------------------------------------------
extern "C" void kernel_launch(void* const* d_in, const int* in_sizes, int n_in,
                              void* d_out, int out_size, void* d_ws, size_t ws_size,
                              hipStream_t stream)
{
    (void)in_sizes; (void)n_in; (void)out_size; (void)ws_size;
    const float* x   = (const float*)d_in[0];
    const float* lng = (const float*)d_in[1];
    const float* lnb = (const float*)d_in[2];
    const float* wq  = (const float*)d_in[3];
    const float* bq  = (const float*)d_in[4];
    const float* wk  = (const float*)d_in[5];
    const float* bk  = (const float*)d_in[6];
    const float* wv  = (const float*)d_in[7];
    const float* bv  = (const float*)d_in[8];
    const float* wo  = (const float*)d_in[9];
    const float* bo  = (const float*)d_in[10];
    const float* rb  = (const float*)d_in[11];
    // d_in[12] (rel_idx) unused: index recomputed analytically in-kernel.

    ushort_t* ws = (ushort_t*)d_ws;
    ushort_t* Xbf = ws;                       // 4194304 elems each
    ushort_t* Qbf = ws + 1 * 4194304;
    ushort_t* Kbf = ws + 2 * 4194304;
    ushort_t* Vbf = ws + 3 * 4194304;
    ushort_t* Obf = ws + 4 * 4194304;
    ushort_t* Wqb = ws + 5 * 4194304;
    ushort_t* Wkb = Wqb + 65536;
    ushort_t* Wvb = Wkb + 65536;
    ushort_t* Wob = Wvb + 65536;
    float* rb2 = (float*)(Wob + 65536);       // 31752 floats, 4B-aligned
    float* out = (float*)d_out;

    hipLaunchKernelGGL(prep_kernel,  dim3(520),  dim3(256), 0, stream,
                       x, lng, lnb, Xbf, wq, wk, wv, wo, Wqb, Wkb, Wvb, Wob, rb, rb2);
    hipLaunchKernelGGL(qkv_kernel,   dim3(1024), dim3(256), 0, stream,
                       Xbf, Wqb, bq, Wkb, bk, Wvb, bv, Qbf, Kbf, Vbf);
    hipLaunchKernelGGL(attn_kernel,  dim3(1024), dim3(256), 0, stream, Qbf, Kbf, Vbf, rb2, Obf);
    hipLaunchKernelGGL(oproj_kernel, dim3(1024), dim3(256), 0, stream, Obf, Wob, bo, x, out);
}